// Round 3
// baseline (296.699 us; speedup 1.0000x reference)
//
#include <hip/hip_runtime.h>
#include <stdint.h>

// CausalMultiHeadSelfAttention: B=2, S=2048, D_MODEL=1024, H=16, DK=64
// Device I/O dtypes: inputs f32 (+ int32 positions), output f32.
// Internal compute: bf16 MFMA with f32 accumulation; intermediates bf16.
// Pipeline: rope tables -> QKV gemm (f32 in, bf16 out; V transposed) ->
//           rope(Q,K) -> causal flash attention -> output gemm (f32 out).
// Q,K intermediates live in d_out (fully consumed before final overwrite).

typedef unsigned short u16;
typedef __bf16 bf16x8 __attribute__((ext_vector_type(8)));
typedef float f32x4 __attribute__((ext_vector_type(4)));
typedef u16 u16x4 __attribute__((ext_vector_type(4)));

#define LOG2E 1.44269504088896340736f

static __device__ __forceinline__ u16 f2bf(float f) {
  union { float f; uint32_t u; } v; v.f = f;
  uint32_t u = v.u;
  return (u16)((u + 0x7FFFu + ((u >> 16) & 1u)) >> 16);  // RNE
}
static __device__ __forceinline__ float bf2f(u16 h) {
  union { uint32_t u; float f; } v; v.u = ((uint32_t)h) << 16; return v.f;
}

// load 8 contiguous elements as bf16x8; F32 sources are converted (RNE cvt_pk).
template<bool F32>
static __device__ __forceinline__ bf16x8 load8(const void* p, size_t off) {
  if constexpr (F32) {
    const float* f = (const float*)p + off;
    f32x4 a = *(const f32x4*)f;
    f32x4 b = *(const f32x4*)(f + 4);
    bf16x8 r;
    r[0] = (__bf16)a[0]; r[1] = (__bf16)a[1]; r[2] = (__bf16)a[2]; r[3] = (__bf16)a[3];
    r[4] = (__bf16)b[0]; r[5] = (__bf16)b[1]; r[6] = (__bf16)b[2]; r[7] = (__bf16)b[3];
    return r;
  } else {
    return *(const bf16x8*)((const u16*)p + off);
  }
}

// ---------------------------------------------------------------- rope tables
__global__ void rope_tables_kernel(const int* __restrict__ tp,
                                   float* __restrict__ cosT, float* __restrict__ sinT) {
  int idx = blockIdx.x * 256 + threadIdx.x;          // 2048*32
  if (idx >= 2048 * 32) return;
  int s = idx >> 5, i = idx & 31;
  float p = (float)tp[s];
  float freq = powf(10000.0f, -(float)i / 32.0f);    // theta^(-2i/64)
  float ang = p * freq;
  cosT[idx] = cosf(ang);
  sinT[idx] = sinf(ang);
}

// ------------------------------------------------------------- 128x128 gemm core
// C[row][col] = sum_k A[row][k] * W[col][k]   (x @ W.T; both K-contiguous)
// 256 thr = 4 waves in 2x2, each wave 64x64 (4x4 frags of 16x16x32 bf16 MFMA).
template<bool AF32, bool BF32>
static __device__ __forceinline__ void gemm128_core(
    const void* __restrict__ A, const void* __restrict__ W,
    u16* As, u16* Bs, int m0, int n0, f32x4 (&acc)[4][4]) {
  const int tid = threadIdx.x;
  const int lane = tid & 63;
  const int wave = tid >> 6;
  const int wr = (wave >> 1) * 64, wc = (wave & 1) * 64;
  const int lr = lane & 15, lg = lane >> 4;
  const int srow = tid >> 2;            // 0..63
  const int scol = (tid & 3) * 8;       // k element offset
  for (int k0 = 0; k0 < 1024; k0 += 32) {
    bf16x8 ta0 = load8<AF32>(A, (size_t)(m0 + srow) * 1024 + k0 + scol);
    bf16x8 ta1 = load8<AF32>(A, (size_t)(m0 + 64 + srow) * 1024 + k0 + scol);
    bf16x8 tb0 = load8<BF32>(W, (size_t)(n0 + srow) * 1024 + k0 + scol);
    bf16x8 tb1 = load8<BF32>(W, (size_t)(n0 + 64 + srow) * 1024 + k0 + scol);
    __syncthreads();   // protect previous iteration's LDS reads
    *(bf16x8*)(As + tid * 8)        = ta0;   // row=tid/4, cols (tid%4)*8..+8
    *(bf16x8*)(As + 2048 + tid * 8) = ta1;
    *(bf16x8*)(Bs + tid * 8)        = tb0;
    *(bf16x8*)(Bs + 2048 + tid * 8) = tb1;
    __syncthreads();
    bf16x8 af[4], bfr[4];
#pragma unroll
    for (int i = 0; i < 4; ++i) {
      af[i]  = *(const bf16x8*)(As + (wr + i * 16 + lr) * 32 + lg * 8);
      bfr[i] = *(const bf16x8*)(Bs + (wc + i * 16 + lr) * 32 + lg * 8);
    }
#pragma unroll
    for (int i = 0; i < 4; ++i)
#pragma unroll
      for (int j = 0; j < 4; ++j)
        acc[i][j] = __builtin_amdgcn_mfma_f32_16x16x32_bf16(af[i], bfr[j], acc[i][j], 0, 0, 0);
  }
}

// ------------------------------------------------------------------ QKV gemm
// z=0: Q -> (B,H,S,64); z=1: K -> (B,H,S,64); z=2: V -> (B,H,64,S) transposed.
__global__ __launch_bounds__(256, 2)
void qkv_gemm_kernel(const float* __restrict__ X,
                     const float* __restrict__ Wq, const float* __restrict__ Wk,
                     const float* __restrict__ Wv,
                     u16* __restrict__ Qo, u16* __restrict__ Ko, u16* __restrict__ Vto) {
  __shared__ __align__(16) u16 As[128 * 32];
  __shared__ __align__(16) u16 Bs[128 * 32];
  const int z = blockIdx.z;
  const float* W = (z == 0) ? Wq : ((z == 1) ? Wk : Wv);
  const int m0 = blockIdx.x * 128, n0 = blockIdx.y * 128;
  f32x4 acc[4][4] = {};
  gemm128_core<true, true>(X, W, As, Bs, m0, n0, acc);
  const int lane = threadIdx.x & 63, wave = threadIdx.x >> 6;
  const int wr = (wave >> 1) * 64, wc = (wave & 1) * 64;
  const int lr = lane & 15, lg = lane >> 4;
  if (z < 2) {
    u16* dst = z ? Ko : Qo;
#pragma unroll
    for (int i = 0; i < 4; ++i) {
      const int rb = m0 + wr + i * 16 + lg * 4;  // global row = b*2048+s
#pragma unroll
      for (int n = 0; n < 4; ++n) {
        const int c = n0 + wc + n * 16 + lr;     // feature -> h,d
        const int hh = c >> 6, d = c & 63;
#pragma unroll
        for (int j = 0; j < 4; ++j) {
          const int r = rb + j;
          dst[(((size_t)(r >> 11) * 16 + hh) * 2048 + (r & 2047)) * 64 + d] =
              f2bf(acc[i][n][j]);
        }
      }
    }
  } else {  // V transposed: 4 consecutive rows (j) pack into one 8B store
#pragma unroll
    for (int i = 0; i < 4; ++i) {
      const int s0 = m0 + wr + i * 16 + lg * 4;
      const int bb = s0 >> 11, ss = s0 & 2047;
#pragma unroll
      for (int n = 0; n < 4; ++n) {
        const int c = n0 + wc + n * 16 + lr;
        const int hh = c >> 6, d = c & 63;
        u16x4 pk;
#pragma unroll
        for (int j = 0; j < 4; ++j) pk[j] = f2bf(acc[i][n][j]);
        *(u16x4*)(Vto + (((size_t)bb * 16 + hh) * 64 + d) * 2048 + ss) = pk;
      }
    }
  }
}

// ------------------------------------------------------------------ RoPE apply
__global__ void rope_apply_kernel(u16* __restrict__ Qb, u16* __restrict__ Kb,
                                  const float* __restrict__ cosT,
                                  const float* __restrict__ sinT, int total) {
  int g = blockIdx.x * 256 + threadIdx.x;
  if (g >= total) return;
  int chunk = g & 7;            // which 8-elem group within d=64
  int s = (g >> 3) & 2047;
  size_t base = (size_t)g * 8;
  int fi = s * 32 + chunk * 4;  // freq index of first pair
  float cv[4], sv[4];
#pragma unroll
  for (int j = 0; j < 4; ++j) { cv[j] = cosT[fi + j]; sv[j] = sinT[fi + j]; }
  u16x4 q0 = *(u16x4*)(Qb + base), q1 = *(u16x4*)(Qb + base + 4);
  u16x4 k0 = *(u16x4*)(Kb + base), k1 = *(u16x4*)(Kb + base + 4);
  u16 qi[8] = {q0[0], q0[1], q0[2], q0[3], q1[0], q1[1], q1[2], q1[3]};
  u16 ki[8] = {k0[0], k0[1], k0[2], k0[3], k1[0], k1[1], k1[2], k1[3]};
  u16 qo[8], ko[8];
#pragma unroll
  for (int j = 0; j < 4; ++j) {
    float e = bf2f(qi[2 * j]), o = bf2f(qi[2 * j + 1]);
    qo[2 * j]     = f2bf(e * cv[j] - o * sv[j]);
    qo[2 * j + 1] = f2bf(e * sv[j] + o * cv[j]);
    e = bf2f(ki[2 * j]); o = bf2f(ki[2 * j + 1]);
    ko[2 * j]     = f2bf(e * cv[j] - o * sv[j]);
    ko[2 * j + 1] = f2bf(e * sv[j] + o * cv[j]);
  }
  u16x4 a{qo[0], qo[1], qo[2], qo[3]}, b{qo[4], qo[5], qo[6], qo[7]};
  u16x4 c{ko[0], ko[1], ko[2], ko[3]}, d{ko[4], ko[5], ko[6], ko[7]};
  *(u16x4*)(Qb + base) = a; *(u16x4*)(Qb + base + 4) = b;
  *(u16x4*)(Kb + base) = c; *(u16x4*)(Kb + base + 4) = d;
}

// ------------------------------------------------------------- flash attention
// grid (16 q-tiles, B*16 heads), 256 thr. Wave w owns 32 q-rows; KVBLK=64.
// K (B,H,S,64) and Vt (B,H,64,S) read directly from global (L2-resident).
// No __syncthreads: per-wave LDS region, per-wave causal trip count.
// Ps is XOR-swizzled: element (row, col) stored at col ^ ((row&7)<<3)
// -> b128 reads stay 16B-aligned (row stride 128B), ~2-way banked.
__global__ __launch_bounds__(256, 2)
void flash_attn_kernel(const u16* __restrict__ Q, const u16* __restrict__ K,
                       const u16* __restrict__ Vt, u16* __restrict__ O) {
  __shared__ __align__(16) u16 Ps[4][32][64];
  const int qt = blockIdx.x;
  const int bh = blockIdx.y;
  const int b = bh >> 4, h = bh & 15;
  const int tid = threadIdx.x;
  const int wave = tid >> 6, lane = tid & 63;
  const int lr = lane & 15, lg = lane >> 4;
  const int qbase = qt * 128 + wave * 32;
  const size_t hb = (size_t)bh * (2048 * 64);
  const u16* Qh = Q + hb;
  const u16* Kh = K + hb;
  const u16* Vh = Vt + hb;

  bf16x8 qf[2][2];  // hoisted Q fragments
#pragma unroll
  for (int m = 0; m < 2; ++m)
#pragma unroll
    for (int kk = 0; kk < 2; ++kk)
      qf[m][kk] = *(const bf16x8*)(Qh + (size_t)(qbase + m * 16 + lr) * 64 + kk * 32 + lg * 8);

  f32x4 accO[2][4] = {};
  float mrow[2][4], lrow[2][4];
#pragma unroll
  for (int m = 0; m < 2; ++m)
#pragma unroll
    for (int j = 0; j < 4; ++j) { mrow[m][j] = -1e30f; lrow[m][j] = 0.f; }

  const int ntiles = (qbase + 32 + 63) >> 6;
  for (int t = 0; t < ntiles; ++t) {
    const int kv0 = t * 64;
    f32x4 sacc[2][4] = {};
#pragma unroll
    for (int n = 0; n < 4; ++n) {
#pragma unroll
      for (int kk = 0; kk < 2; ++kk) {
        bf16x8 kf = *(const bf16x8*)(Kh + (size_t)(kv0 + n * 16 + lr) * 64 + kk * 32 + lg * 8);
        sacc[0][n] = __builtin_amdgcn_mfma_f32_16x16x32_bf16(qf[0][kk], kf, sacc[0][n], 0, 0, 0);
        sacc[1][n] = __builtin_amdgcn_mfma_f32_16x16x32_bf16(qf[1][kk], kf, sacc[1][n], 0, 0, 0);
      }
    }
    const bool needmask = (kv0 + 63) > qbase;
#pragma unroll
    for (int m = 0; m < 2; ++m)
#pragma unroll
      for (int n = 0; n < 4; ++n)
#pragma unroll
        for (int j = 0; j < 4; ++j) {
          float v = sacc[m][n][j] * 0.125f;   // 1/sqrt(64)
          if (needmask) {
            int c = kv0 + n * 16 + lr;
            int r = qbase + m * 16 + lg * 4 + j;
            if (c > r) v = -1e30f;
          }
          sacc[m][n][j] = v;
        }
#pragma unroll
    for (int m = 0; m < 2; ++m) {
      float pj[4][4], al[4];
#pragma unroll
      for (int j = 0; j < 4; ++j) {
        float tm = fmaxf(fmaxf(sacc[m][0][j], sacc[m][1][j]),
                         fmaxf(sacc[m][2][j], sacc[m][3][j]));
        tm = fmaxf(tm, __shfl_xor(tm, 1));
        tm = fmaxf(tm, __shfl_xor(tm, 2));
        tm = fmaxf(tm, __shfl_xor(tm, 4));
        tm = fmaxf(tm, __shfl_xor(tm, 8));
        float mn = fmaxf(mrow[m][j], tm);
        al[j] = exp2f((mrow[m][j] - mn) * LOG2E);
        mrow[m][j] = mn;
        float ssum = 0.f;
#pragma unroll
        for (int n = 0; n < 4; ++n) {
          float p = exp2f((sacc[m][n][j] - mn) * LOG2E);
          pj[n][j] = p;
          ssum += p;
        }
        ssum += __shfl_xor(ssum, 1);
        ssum += __shfl_xor(ssum, 2);
        ssum += __shfl_xor(ssum, 4);
        ssum += __shfl_xor(ssum, 8);
        lrow[m][j] = lrow[m][j] * al[j] + ssum;
      }
#pragma unroll
      for (int n = 0; n < 4; ++n)
#pragma unroll
        for (int j = 0; j < 4; ++j)
          accO[m][n][j] *= al[j];
#pragma unroll
      for (int n = 0; n < 4; ++n)
#pragma unroll
        for (int j = 0; j < 4; ++j) {
          const int row = m * 16 + lg * 4 + j;
          const int col = n * 16 + lr;
          Ps[wave][row][col ^ ((row & 7) << 3)] = f2bf(pj[n][j]);
        }
    }
    // PV: P (A-frag from swizzled LDS), V (B-frag from Vt, contiguous)
#pragma unroll
    for (int ks = 0; ks < 2; ++ks) {
      const int swg = (((ks * 4 + lg) ^ (lr & 7)) << 3);
      bf16x8 pa0 = *(const bf16x8*)&Ps[wave][lr][swg];
      bf16x8 pa1 = *(const bf16x8*)&Ps[wave][16 + lr][swg];
#pragma unroll
      for (int n = 0; n < 4; ++n) {
        bf16x8 vf = *(const bf16x8*)(Vh + (size_t)(n * 16 + lr) * 2048 + kv0 + ks * 32 + lg * 8);
        accO[0][n] = __builtin_amdgcn_mfma_f32_16x16x32_bf16(pa0, vf, accO[0][n], 0, 0, 0);
        accO[1][n] = __builtin_amdgcn_mfma_f32_16x16x32_bf16(pa1, vf, accO[1][n], 0, 0, 0);
      }
    }
  }
#pragma unroll
  for (int m = 0; m < 2; ++m) {
    float inv[4];
#pragma unroll
    for (int j = 0; j < 4; ++j) inv[j] = 1.0f / lrow[m][j];
#pragma unroll
    for (int n = 0; n < 4; ++n) {
      const int d = n * 16 + lr;
#pragma unroll
      for (int j = 0; j < 4; ++j) {
        const int r = qbase + m * 16 + lg * 4 + j;
        O[((size_t)(b * 2048 + r) * 16 + h) * 64 + d] = f2bf(accO[m][n][j] * inv[j]);
      }
    }
  }
}

// ------------------------------------------------------------ output projection
__global__ __launch_bounds__(256, 2)
void out_gemm_kernel(const u16* __restrict__ A, const float* __restrict__ W,
                     float* __restrict__ out) {
  __shared__ __align__(16) u16 As[128 * 32];
  __shared__ __align__(16) u16 Bs[128 * 32];
  const int m0 = blockIdx.x * 128, n0 = blockIdx.y * 128;
  f32x4 acc[4][4] = {};
  gemm128_core<false, true>(A, W, As, Bs, m0, n0, acc);
  const int lane = threadIdx.x & 63, wave = threadIdx.x >> 6;
  const int wr = (wave >> 1) * 64, wc = (wave & 1) * 64;
  const int lr = lane & 15, lg = lane >> 4;
#pragma unroll
  for (int i = 0; i < 4; ++i)
#pragma unroll
    for (int n = 0; n < 4; ++n) {
      const int c = n0 + wc + n * 16 + lr;
#pragma unroll
      for (int j = 0; j < 4; ++j) {
        const int r = m0 + wr + i * 16 + lg * 4 + j;
        out[(size_t)r * 1024 + c] = acc[i][n][j];   // f32 store, no rounding
      }
    }
}

// --------------------------------------------------------------------- launch
extern "C" void kernel_launch(void* const* d_in, const int* in_sizes, int n_in,
                              void* d_out, int out_size, void* d_ws, size_t ws_size,
                              hipStream_t stream) {
  const float* x  = (const float*)d_in[0];
  const int*   tp = (const int*)d_in[1];
  const float* Wq = (const float*)d_in[2];
  const float* Wk = (const float*)d_in[3];
  const float* Wv = (const float*)d_in[4];
  const float* Wo = (const float*)d_in[5];
  float* out = (float*)d_out;
  const int B = in_sizes[0] / (2048 * 1024);
  const size_t tsz = (size_t)B * 2048 * 1024 * sizeof(u16);  // 8MB @ B=2
  // Q,K (bf16) live inside d_out (f32 out = 2*tsz bytes); fully consumed by
  // flash_attn before out_gemm overwrites d_out. Vt, Ob, tables in d_ws.
  u16* Qb = (u16*)d_out;
  u16* Kb = (u16*)((char*)d_out + tsz);
  char* ws = (char*)d_ws;
  u16* Vt = (u16*)(ws);
  u16* Ob = (u16*)(ws + tsz);
  float* cosT = (float*)(ws + 2 * tsz);
  float* sinT = cosT + 2048 * 32;

  rope_tables_kernel<<<dim3(256), dim3(256), 0, stream>>>(tp, cosT, sinT);
  qkv_gemm_kernel<<<dim3(B * 16, 8, 3), dim3(256), 0, stream>>>(x, Wq, Wk, Wv, Qb, Kb, Vt);
  rope_apply_kernel<<<dim3(B * 16 * 2048 * 8 / 256), dim3(256), 0, stream>>>(
      Qb, Kb, cosT, sinT, B * 16 * 2048 * 8);
  flash_attn_kernel<<<dim3(16, B * 16), dim3(256), 0, stream>>>(Qb, Kb, Vt, Ob);
  out_gemm_kernel<<<dim3(B * 16, 8), dim3(256), 0, stream>>>(Ob, Wo, out);
}

// Round 4
// 223.191 us; speedup vs baseline: 1.3294x; 1.3294x over previous
//
#include <hip/hip_runtime.h>
#include <stdint.h>

// CausalMultiHeadSelfAttention: B=2, S=2048, D_MODEL=1024, H=16, DK=64
// Device I/O dtypes: inputs f32 (+ int32 positions), output f32.
// Internal compute: bf16 MFMA with f32 accumulation; intermediates bf16.
// Pipeline: rope tables -> QKV gemm (f32 in, bf16 out; V transposed) ->
//           rope(Q,K; Q pre-scaled by 0.125*log2e) -> causal flash attention
//           (16 q-rows/wave, heavy-first, mask split out) -> out gemm (f32).
// Q,K intermediates live in d_out (fully consumed before final overwrite).

typedef unsigned short u16;
typedef __bf16 bf16x8 __attribute__((ext_vector_type(8)));
typedef float f32x4 __attribute__((ext_vector_type(4)));
typedef u16 u16x4 __attribute__((ext_vector_type(4)));

#define LOG2E 1.44269504088896340736f
#define QSCALE (0.125f * LOG2E)   // folded into Q at rope time

static __device__ __forceinline__ u16 f2bf(float f) {
  union { float f; uint32_t u; } v; v.f = f;
  uint32_t u = v.u;
  return (u16)((u + 0x7FFFu + ((u >> 16) & 1u)) >> 16);  // RNE
}
static __device__ __forceinline__ float bf2f(u16 h) {
  union { uint32_t u; float f; } v; v.u = ((uint32_t)h) << 16; return v.f;
}

// load 8 contiguous elements as bf16x8; F32 sources are converted (RNE cvt_pk).
template<bool F32>
static __device__ __forceinline__ bf16x8 load8(const void* p, size_t off) {
  if constexpr (F32) {
    const float* f = (const float*)p + off;
    f32x4 a = *(const f32x4*)f;
    f32x4 b = *(const f32x4*)(f + 4);
    bf16x8 r;
    r[0] = (__bf16)a[0]; r[1] = (__bf16)a[1]; r[2] = (__bf16)a[2]; r[3] = (__bf16)a[3];
    r[4] = (__bf16)b[0]; r[5] = (__bf16)b[1]; r[6] = (__bf16)b[2]; r[7] = (__bf16)b[3];
    return r;
  } else {
    return *(const bf16x8*)((const u16*)p + off);
  }
}

// ---------------------------------------------------------------- rope tables
__global__ void rope_tables_kernel(const int* __restrict__ tp,
                                   float* __restrict__ cosT, float* __restrict__ sinT) {
  int idx = blockIdx.x * 256 + threadIdx.x;          // 2048*32
  if (idx >= 2048 * 32) return;
  int s = idx >> 5, i = idx & 31;
  float p = (float)tp[s];
  float freq = powf(10000.0f, -(float)i / 32.0f);    // theta^(-2i/64)
  float ang = p * freq;
  cosT[idx] = cosf(ang);
  sinT[idx] = sinf(ang);
}

// ------------------------------------------------------------- 128x128 gemm core
template<bool AF32, bool BF32>
static __device__ __forceinline__ void gemm128_core(
    const void* __restrict__ A, const void* __restrict__ W,
    u16* As, u16* Bs, int m0, int n0, f32x4 (&acc)[4][4]) {
  const int tid = threadIdx.x;
  const int lane = tid & 63;
  const int wave = tid >> 6;
  const int wr = (wave >> 1) * 64, wc = (wave & 1) * 64;
  const int lr = lane & 15, lg = lane >> 4;
  const int srow = tid >> 2;            // 0..63
  const int scol = (tid & 3) * 8;       // k element offset
  for (int k0 = 0; k0 < 1024; k0 += 32) {
    bf16x8 ta0 = load8<AF32>(A, (size_t)(m0 + srow) * 1024 + k0 + scol);
    bf16x8 ta1 = load8<AF32>(A, (size_t)(m0 + 64 + srow) * 1024 + k0 + scol);
    bf16x8 tb0 = load8<BF32>(W, (size_t)(n0 + srow) * 1024 + k0 + scol);
    bf16x8 tb1 = load8<BF32>(W, (size_t)(n0 + 64 + srow) * 1024 + k0 + scol);
    __syncthreads();   // protect previous iteration's LDS reads
    *(bf16x8*)(As + tid * 8)        = ta0;
    *(bf16x8*)(As + 2048 + tid * 8) = ta1;
    *(bf16x8*)(Bs + tid * 8)        = tb0;
    *(bf16x8*)(Bs + 2048 + tid * 8) = tb1;
    __syncthreads();
    bf16x8 af[4], bfr[4];
#pragma unroll
    for (int i = 0; i < 4; ++i) {
      af[i]  = *(const bf16x8*)(As + (wr + i * 16 + lr) * 32 + lg * 8);
      bfr[i] = *(const bf16x8*)(Bs + (wc + i * 16 + lr) * 32 + lg * 8);
    }
#pragma unroll
    for (int i = 0; i < 4; ++i)
#pragma unroll
      for (int j = 0; j < 4; ++j)
        acc[i][j] = __builtin_amdgcn_mfma_f32_16x16x32_bf16(af[i], bfr[j], acc[i][j], 0, 0, 0);
  }
}

// ------------------------------------------------------------------ QKV gemm
// z=0: Q -> (B,H,S,64); z=1: K -> (B,H,S,64); z=2: V -> (B,H,64,S) transposed.
__global__ __launch_bounds__(256, 2)
void qkv_gemm_kernel(const float* __restrict__ X,
                     const float* __restrict__ Wq, const float* __restrict__ Wk,
                     const float* __restrict__ Wv,
                     u16* __restrict__ Qo, u16* __restrict__ Ko, u16* __restrict__ Vto) {
  __shared__ __align__(16) u16 As[128 * 32];
  __shared__ __align__(16) u16 Bs[128 * 32];
  const int z = blockIdx.z;
  const float* W = (z == 0) ? Wq : ((z == 1) ? Wk : Wv);
  const int m0 = blockIdx.x * 128, n0 = blockIdx.y * 128;
  f32x4 acc[4][4] = {};
  gemm128_core<true, true>(X, W, As, Bs, m0, n0, acc);
  const int lane = threadIdx.x & 63, wave = threadIdx.x >> 6;
  const int wr = (wave >> 1) * 64, wc = (wave & 1) * 64;
  const int lr = lane & 15, lg = lane >> 4;
  if (z < 2) {
    u16* dst = z ? Ko : Qo;
#pragma unroll
    for (int i = 0; i < 4; ++i) {
      const int rb = m0 + wr + i * 16 + lg * 4;  // global row = b*2048+s
#pragma unroll
      for (int n = 0; n < 4; ++n) {
        const int c = n0 + wc + n * 16 + lr;     // feature -> h,d
        const int hh = c >> 6, d = c & 63;
#pragma unroll
        for (int j = 0; j < 4; ++j) {
          const int r = rb + j;
          dst[(((size_t)(r >> 11) * 16 + hh) * 2048 + (r & 2047)) * 64 + d] =
              f2bf(acc[i][n][j]);
        }
      }
    }
  } else {  // V transposed: 4 consecutive rows (j) pack into one 8B store
#pragma unroll
    for (int i = 0; i < 4; ++i) {
      const int s0 = m0 + wr + i * 16 + lg * 4;
      const int bb = s0 >> 11, ss = s0 & 2047;
#pragma unroll
      for (int n = 0; n < 4; ++n) {
        const int c = n0 + wc + n * 16 + lr;
        const int hh = c >> 6, d = c & 63;
        u16x4 pk;
#pragma unroll
        for (int j = 0; j < 4; ++j) pk[j] = f2bf(acc[i][n][j]);
        *(u16x4*)(Vto + (((size_t)bb * 16 + hh) * 64 + d) * 2048 + ss) = pk;
      }
    }
  }
}

// ------------------------------------------------------------------ RoPE apply
// Q additionally scaled by QSCALE = 0.125*log2(e): folds the attention scale
// and the exp->exp2 conversion into the GEMM output (saves VALU in flash).
__global__ void rope_apply_kernel(u16* __restrict__ Qb, u16* __restrict__ Kb,
                                  const float* __restrict__ cosT,
                                  const float* __restrict__ sinT, int total) {
  int g = blockIdx.x * 256 + threadIdx.x;
  if (g >= total) return;
  int chunk = g & 7;            // which 8-elem group within d=64
  int s = (g >> 3) & 2047;
  size_t base = (size_t)g * 8;
  int fi = s * 32 + chunk * 4;  // freq index of first pair
  float cv[4], sv[4];
#pragma unroll
  for (int j = 0; j < 4; ++j) { cv[j] = cosT[fi + j]; sv[j] = sinT[fi + j]; }
  u16x4 q0 = *(u16x4*)(Qb + base), q1 = *(u16x4*)(Qb + base + 4);
  u16x4 k0 = *(u16x4*)(Kb + base), k1 = *(u16x4*)(Kb + base + 4);
  u16 qi[8] = {q0[0], q0[1], q0[2], q0[3], q1[0], q1[1], q1[2], q1[3]};
  u16 ki[8] = {k0[0], k0[1], k0[2], k0[3], k1[0], k1[1], k1[2], k1[3]};
  u16 qo[8], ko[8];
#pragma unroll
  for (int j = 0; j < 4; ++j) {
    float e = bf2f(qi[2 * j]), o = bf2f(qi[2 * j + 1]);
    qo[2 * j]     = f2bf((e * cv[j] - o * sv[j]) * QSCALE);
    qo[2 * j + 1] = f2bf((e * sv[j] + o * cv[j]) * QSCALE);
    e = bf2f(ki[2 * j]); o = bf2f(ki[2 * j + 1]);
    ko[2 * j]     = f2bf(e * cv[j] - o * sv[j]);
    ko[2 * j + 1] = f2bf(e * sv[j] + o * cv[j]);
  }
  u16x4 a{qo[0], qo[1], qo[2], qo[3]}, b{qo[4], qo[5], qo[6], qo[7]};
  u16x4 c{ko[0], ko[1], ko[2], ko[3]}, d{ko[4], ko[5], ko[6], ko[7]};
  *(u16x4*)(Qb + base) = a; *(u16x4*)(Qb + base + 4) = b;
  *(u16x4*)(Kb + base) = c; *(u16x4*)(Kb + base + 4) = d;
}

// ------------------------------------------------------------- flash attention
// One 64-KV-tile step for a 16-row q chunk. Scores arrive pre-scaled in the
// log2 domain (QSCALE folded into Q), so softmax uses exp2 directly.
template<bool MASKED>
static __device__ __forceinline__ void attn_tile(
    const u16* __restrict__ Kh, const u16* __restrict__ Vh,
    int kv0, int qbase, const bf16x8 (&qf)[2], u16 (*Ps)[64],
    f32x4 (&accO)[4], float (&mrow)[4], float (&lrow)[4],
    int lr, int lg) {
  f32x4 sacc[4] = {};
#pragma unroll
  for (int n = 0; n < 4; ++n)
#pragma unroll
    for (int kk = 0; kk < 2; ++kk) {
      bf16x8 kf = *(const bf16x8*)(Kh + (size_t)(kv0 + n * 16 + lr) * 64 + kk * 32 + lg * 8);
      sacc[n] = __builtin_amdgcn_mfma_f32_16x16x32_bf16(qf[kk], kf, sacc[n], 0, 0, 0);
    }
  if (MASKED) {
#pragma unroll
    for (int n = 0; n < 4; ++n) {
      const int c = kv0 + n * 16 + lr;
#pragma unroll
      for (int j = 0; j < 4; ++j) {
        const int r = qbase + lg * 4 + j;
        if (c > r) sacc[n][j] = -1e30f;
      }
    }
  }
  float pj[4][4], al[4];
#pragma unroll
  for (int j = 0; j < 4; ++j) {
    float tm = fmaxf(fmaxf(sacc[0][j], sacc[1][j]), fmaxf(sacc[2][j], sacc[3][j]));
    tm = fmaxf(tm, __shfl_xor(tm, 1));
    tm = fmaxf(tm, __shfl_xor(tm, 2));
    tm = fmaxf(tm, __shfl_xor(tm, 4));
    tm = fmaxf(tm, __shfl_xor(tm, 8));
    float mn = fmaxf(mrow[j], tm);
    al[j] = exp2f(mrow[j] - mn);
    mrow[j] = mn;
    float ssum = 0.f;
#pragma unroll
    for (int n = 0; n < 4; ++n) {
      float p = exp2f(sacc[n][j] - mn);
      pj[n][j] = p;
      ssum += p;
    }
    ssum += __shfl_xor(ssum, 1);
    ssum += __shfl_xor(ssum, 2);
    ssum += __shfl_xor(ssum, 4);
    ssum += __shfl_xor(ssum, 8);
    lrow[j] = lrow[j] * al[j] + ssum;
  }
#pragma unroll
  for (int n = 0; n < 4; ++n)
#pragma unroll
    for (int j = 0; j < 4; ++j)
      accO[n][j] *= al[j];
#pragma unroll
  for (int n = 0; n < 4; ++n)
#pragma unroll
    for (int j = 0; j < 4; ++j) {
      const int row = lg * 4 + j;
      Ps[row][(n * 16 + lr) ^ ((row & 7) << 3)] = f2bf(pj[n][j]);
    }
#pragma unroll
  for (int ks = 0; ks < 2; ++ks) {
    const int swg = (((ks * 4 + lg) ^ (lr & 7)) << 3);
    bf16x8 pa = *(const bf16x8*)&Ps[lr][swg];
#pragma unroll
    for (int n = 0; n < 4; ++n) {
      bf16x8 vf = *(const bf16x8*)(Vh + (size_t)(n * 16 + lr) * 2048 + kv0 + ks * 32 + lg * 8);
      accO[n] = __builtin_amdgcn_mfma_f32_16x16x32_bf16(pa, vf, accO[n], 0, 0, 0);
    }
  }
}

// grid (32 bh, 64 q-chunks reversed), 128 thr = 2 waves; wave owns 16 q-rows.
// Heavy chunks (long causal trip counts) dispatch first -> short blocks fill
// the scheduling tail. Exactly one straddling tile needs the causal mask.
__global__ __launch_bounds__(128, 4)
void flash_attn_kernel(const u16* __restrict__ Q, const u16* __restrict__ K,
                       const u16* __restrict__ Vt, u16* __restrict__ O) {
  __shared__ __align__(16) u16 Ps[2][16][64];
  const int bh = blockIdx.x;
  const int qc = 63 - (int)blockIdx.y;     // heavy-first
  const int b = bh >> 4, h = bh & 15;
  const int tid = threadIdx.x;
  const int wave = tid >> 6, lane = tid & 63;
  const int lr = lane & 15, lg = lane >> 4;
  const int qbase = qc * 32 + wave * 16;
  const size_t hb = (size_t)bh * (2048 * 64);
  const u16* Qh = Q + hb;
  const u16* Kh = K + hb;
  const u16* Vh = Vt + hb;

  bf16x8 qf[2];
#pragma unroll
  for (int kk = 0; kk < 2; ++kk)
    qf[kk] = *(const bf16x8*)(Qh + (size_t)(qbase + lr) * 64 + kk * 32 + lg * 8);

  f32x4 accO[4] = {};
  float mrow[4], lrow[4];
#pragma unroll
  for (int j = 0; j < 4; ++j) { mrow[j] = -1e30f; lrow[j] = 0.f; }

  const int nfull = qbase >> 6;            // tiles fully below the diagonal
  for (int t = 0; t < nfull; ++t)
    attn_tile<false>(Kh, Vh, t * 64, qbase, qf, Ps[wave], accO, mrow, lrow, lr, lg);
  attn_tile<true>(Kh, Vh, nfull * 64, qbase, qf, Ps[wave], accO, mrow, lrow, lr, lg);

  float inv[4];
#pragma unroll
  for (int j = 0; j < 4; ++j) inv[j] = 1.0f / lrow[j];
#pragma unroll
  for (int n = 0; n < 4; ++n) {
    const int d = n * 16 + lr;
#pragma unroll
    for (int j = 0; j < 4; ++j) {
      const int r = qbase + lg * 4 + j;
      O[((size_t)(b * 2048 + r) * 16 + h) * 64 + d] = f2bf(accO[n][j] * inv[j]);
    }
  }
}

// ------------------------------------------------------------ output projection
__global__ __launch_bounds__(256, 2)
void out_gemm_kernel(const u16* __restrict__ A, const float* __restrict__ W,
                     float* __restrict__ out) {
  __shared__ __align__(16) u16 As[128 * 32];
  __shared__ __align__(16) u16 Bs[128 * 32];
  const int m0 = blockIdx.x * 128, n0 = blockIdx.y * 128;
  f32x4 acc[4][4] = {};
  gemm128_core<false, true>(A, W, As, Bs, m0, n0, acc);
  const int lane = threadIdx.x & 63, wave = threadIdx.x >> 6;
  const int wr = (wave >> 1) * 64, wc = (wave & 1) * 64;
  const int lr = lane & 15, lg = lane >> 4;
#pragma unroll
  for (int i = 0; i < 4; ++i)
#pragma unroll
    for (int n = 0; n < 4; ++n) {
      const int c = n0 + wc + n * 16 + lr;
#pragma unroll
      for (int j = 0; j < 4; ++j) {
        const int r = m0 + wr + i * 16 + lg * 4 + j;
        out[(size_t)r * 1024 + c] = acc[i][n][j];   // f32 store, no rounding
      }
    }
}

// --------------------------------------------------------------------- launch
extern "C" void kernel_launch(void* const* d_in, const int* in_sizes, int n_in,
                              void* d_out, int out_size, void* d_ws, size_t ws_size,
                              hipStream_t stream) {
  const float* x  = (const float*)d_in[0];
  const int*   tp = (const int*)d_in[1];
  const float* Wq = (const float*)d_in[2];
  const float* Wk = (const float*)d_in[3];
  const float* Wv = (const float*)d_in[4];
  const float* Wo = (const float*)d_in[5];
  float* out = (float*)d_out;
  const int B = in_sizes[0] / (2048 * 1024);
  const size_t tsz = (size_t)B * 2048 * 1024 * sizeof(u16);  // 8MB @ B=2
  // Q,K (bf16) live inside d_out (f32 out = 2*tsz bytes); fully consumed by
  // flash_attn before out_gemm overwrites d_out. Vt, Ob, tables in d_ws.
  u16* Qb = (u16*)d_out;
  u16* Kb = (u16*)((char*)d_out + tsz);
  char* ws = (char*)d_ws;
  u16* Vt = (u16*)(ws);
  u16* Ob = (u16*)(ws + tsz);
  float* cosT = (float*)(ws + 2 * tsz);
  float* sinT = cosT + 2048 * 32;

  rope_tables_kernel<<<dim3(256), dim3(256), 0, stream>>>(tp, cosT, sinT);
  qkv_gemm_kernel<<<dim3(B * 16, 8, 3), dim3(256), 0, stream>>>(x, Wq, Wk, Wv, Qb, Kb, Vt);
  rope_apply_kernel<<<dim3(B * 16 * 2048 * 8 / 256), dim3(256), 0, stream>>>(
      Qb, Kb, cosT, sinT, B * 16 * 2048 * 8);
  flash_attn_kernel<<<dim3(B * 16, 64), dim3(128), 0, stream>>>(Qb, Kb, Vt, Ob);
  out_gemm_kernel<<<dim3(B * 16, 8), dim3(256), 0, stream>>>(Ob, Wo, out);
}

// Round 5
// 213.790 us; speedup vs baseline: 1.3878x; 1.0440x over previous
//
#include <hip/hip_runtime.h>
#include <stdint.h>

// CausalMultiHeadSelfAttention: B=2, S=2048, D_MODEL=1024, H=16, DK=64
// I/O: f32 (+ int32 positions). Internal: bf16 MFMA, f32 accum.
// Pipeline: rope tables -> [bf16 pre-convert of X,W*] -> QKV gemm (V^T out) ->
//           rope(Q,K; Q scaled 0.125*log2e) -> causal flash attn (swapped
//           QK^T: S^T in regs, lane-local softmax) -> out gemm (f32 out).
// Q,K live in d_out (consumed by flash before out_gemm overwrites).

typedef unsigned short u16;
typedef __bf16 bf16x8 __attribute__((ext_vector_type(8)));
typedef float f32x4 __attribute__((ext_vector_type(4)));
typedef u16 u16x4 __attribute__((ext_vector_type(4)));

#define LOG2E 1.44269504088896340736f
#define QSCALE (0.125f * LOG2E)   // folded into Q at rope time

static __device__ __forceinline__ u16 f2bf(float f) {
  union { float f; uint32_t u; } v; v.f = f;
  uint32_t u = v.u;
  return (u16)((u + 0x7FFFu + ((u >> 16) & 1u)) >> 16);  // RNE
}
static __device__ __forceinline__ float bf2f(u16 h) {
  union { uint32_t u; float f; } v; v.u = ((uint32_t)h) << 16; return v.f;
}

template<bool F32>
static __device__ __forceinline__ bf16x8 load8(const void* p, size_t off) {
  if constexpr (F32) {
    const float* f = (const float*)p + off;
    f32x4 a = *(const f32x4*)f;
    f32x4 b = *(const f32x4*)(f + 4);
    bf16x8 r;
    r[0] = (__bf16)a[0]; r[1] = (__bf16)a[1]; r[2] = (__bf16)a[2]; r[3] = (__bf16)a[3];
    r[4] = (__bf16)b[0]; r[5] = (__bf16)b[1]; r[6] = (__bf16)b[2]; r[7] = (__bf16)b[3];
    return r;
  } else {
    return *(const bf16x8*)((const u16*)p + off);
  }
}

// async global(16B/lane) -> LDS; dest must be wave-uniform base + lane*16.
static __device__ __forceinline__ void glds16(const u16* g, u16* l) {
  __builtin_amdgcn_global_load_lds(
      (const __attribute__((address_space(1))) unsigned int*)g,
      (__attribute__((address_space(3))) unsigned int*)l, 16, 0, 0);
}

// ---------------------------------------------------------------- rope tables
__global__ void rope_tables_kernel(const int* __restrict__ tp,
                                   float* __restrict__ cosT, float* __restrict__ sinT) {
  int idx = blockIdx.x * 256 + threadIdx.x;          // 2048*32
  if (idx >= 2048 * 32) return;
  int s = idx >> 5, i = idx & 31;
  float p = (float)tp[s];
  float freq = powf(10000.0f, -(float)i / 32.0f);    // theta^(-2i/64)
  float ang = p * freq;
  cosT[idx] = cosf(ang);
  sinT[idx] = sinf(ang);
}

// ------------------------------------------------------------- f32 -> bf16
__global__ void cvt_bf16_kernel(const float* __restrict__ in,
                                u16* __restrict__ out, int n8) {
  int i = blockIdx.x * 256 + threadIdx.x;
  if (i >= n8) return;
  const float* p = in + (size_t)i * 8;
  f32x4 a = *(const f32x4*)p;
  f32x4 b = *(const f32x4*)(p + 4);
  bf16x8 r;
  r[0] = (__bf16)a[0]; r[1] = (__bf16)a[1]; r[2] = (__bf16)a[2]; r[3] = (__bf16)a[3];
  r[4] = (__bf16)b[0]; r[5] = (__bf16)b[1]; r[6] = (__bf16)b[2]; r[7] = (__bf16)b[3];
  *(bf16x8*)(out + (size_t)i * 8) = r;
}

// ------------------------------------------------------------- 128x128 gemm core
// Both bf16 (AF32=BF32=false): async global_load_lds staging.
// Else: reg-staged with inline f32->bf16 conversion.
template<bool AF32, bool BF32>
static __device__ __forceinline__ void gemm128_core(
    const void* __restrict__ A, const void* __restrict__ W,
    u16* As, u16* Bs, int m0, int n0, f32x4 (&acc)[4][4]) {
  const int tid = threadIdx.x;
  const int lane = tid & 63;
  const int wave = tid >> 6;
  const int wr = (wave >> 1) * 64, wc = (wave & 1) * 64;
  const int lr = lane & 15, lg = lane >> 4;
  const int srow = tid >> 2;            // 0..63
  const int scol = (tid & 3) * 8;       // k element offset
  for (int k0 = 0; k0 < 1024; k0 += 32) {
    if constexpr (!AF32 && !BF32) {
      const u16* Ab = (const u16*)A;
      const u16* Wb = (const u16*)W;
      __syncthreads();   // previous iteration's LDS reads done
      glds16(Ab + (size_t)(m0 + srow) * 1024 + k0 + scol, As + tid * 8);
      glds16(Ab + (size_t)(m0 + 64 + srow) * 1024 + k0 + scol, As + 2048 + tid * 8);
      glds16(Wb + (size_t)(n0 + srow) * 1024 + k0 + scol, Bs + tid * 8);
      glds16(Wb + (size_t)(n0 + 64 + srow) * 1024 + k0 + scol, Bs + 2048 + tid * 8);
      __syncthreads();   // vmcnt(0) drained before barrier -> data visible
    } else {
      bf16x8 ta0 = load8<AF32>(A, (size_t)(m0 + srow) * 1024 + k0 + scol);
      bf16x8 ta1 = load8<AF32>(A, (size_t)(m0 + 64 + srow) * 1024 + k0 + scol);
      bf16x8 tb0 = load8<BF32>(W, (size_t)(n0 + srow) * 1024 + k0 + scol);
      bf16x8 tb1 = load8<BF32>(W, (size_t)(n0 + 64 + srow) * 1024 + k0 + scol);
      __syncthreads();
      *(bf16x8*)(As + tid * 8)        = ta0;
      *(bf16x8*)(As + 2048 + tid * 8) = ta1;
      *(bf16x8*)(Bs + tid * 8)        = tb0;
      *(bf16x8*)(Bs + 2048 + tid * 8) = tb1;
      __syncthreads();
    }
    bf16x8 af[4], bfr[4];
#pragma unroll
    for (int i = 0; i < 4; ++i) {
      af[i]  = *(const bf16x8*)(As + (wr + i * 16 + lr) * 32 + lg * 8);
      bfr[i] = *(const bf16x8*)(Bs + (wc + i * 16 + lr) * 32 + lg * 8);
    }
#pragma unroll
    for (int i = 0; i < 4; ++i)
#pragma unroll
      for (int j = 0; j < 4; ++j)
        acc[i][j] = __builtin_amdgcn_mfma_f32_16x16x32_bf16(af[i], bfr[j], acc[i][j], 0, 0, 0);
  }
}

// ------------------------------------------------------------------ QKV gemm
// z=0: Q -> (B,H,S,64); z=1: K -> (B,H,S,64); z=2: V -> (B,H,64,S) transposed.
template<bool F32>
__global__ __launch_bounds__(256, 2)
void qkv_gemm_kernel(const void* __restrict__ X,
                     const void* __restrict__ Wq, const void* __restrict__ Wk,
                     const void* __restrict__ Wv,
                     u16* __restrict__ Qo, u16* __restrict__ Ko, u16* __restrict__ Vto) {
  __shared__ __align__(16) u16 As[128 * 32];
  __shared__ __align__(16) u16 Bs[128 * 32];
  const int z = blockIdx.z;
  const void* W = (z == 0) ? Wq : ((z == 1) ? Wk : Wv);
  const int m0 = blockIdx.x * 128, n0 = blockIdx.y * 128;
  f32x4 acc[4][4] = {};
  gemm128_core<F32, F32>(X, W, As, Bs, m0, n0, acc);
  const int lane = threadIdx.x & 63, wave = threadIdx.x >> 6;
  const int wr = (wave >> 1) * 64, wc = (wave & 1) * 64;
  const int lr = lane & 15, lg = lane >> 4;
  if (z < 2) {
    u16* dst = z ? Ko : Qo;
#pragma unroll
    for (int i = 0; i < 4; ++i) {
      const int rb = m0 + wr + i * 16 + lg * 4;  // global row = b*2048+s
#pragma unroll
      for (int n = 0; n < 4; ++n) {
        const int c = n0 + wc + n * 16 + lr;     // feature -> h,d
        const int hh = c >> 6, d = c & 63;
#pragma unroll
        for (int j = 0; j < 4; ++j) {
          const int r = rb + j;
          dst[(((size_t)(r >> 11) * 16 + hh) * 2048 + (r & 2047)) * 64 + d] =
              f2bf(acc[i][n][j]);
        }
      }
    }
  } else {  // V transposed: 4 consecutive rows (j) pack into one 8B store
#pragma unroll
    for (int i = 0; i < 4; ++i) {
      const int s0 = m0 + wr + i * 16 + lg * 4;
      const int bb = s0 >> 11, ss = s0 & 2047;
#pragma unroll
      for (int n = 0; n < 4; ++n) {
        const int c = n0 + wc + n * 16 + lr;
        const int hh = c >> 6, d = c & 63;
        u16x4 pk;
#pragma unroll
        for (int j = 0; j < 4; ++j) pk[j] = f2bf(acc[i][n][j]);
        *(u16x4*)(Vto + (((size_t)bb * 16 + hh) * 64 + d) * 2048 + ss) = pk;
      }
    }
  }
}

// ------------------------------------------------------------------ RoPE apply
// Q additionally scaled by QSCALE (attention scale + exp->exp2 fold).
__global__ void rope_apply_kernel(u16* __restrict__ Qb, u16* __restrict__ Kb,
                                  const float* __restrict__ cosT,
                                  const float* __restrict__ sinT, int total) {
  int g = blockIdx.x * 256 + threadIdx.x;
  if (g >= total) return;
  int chunk = g & 7;            // which 8-elem group within d=64
  int s = (g >> 3) & 2047;
  size_t base = (size_t)g * 8;
  int fi = s * 32 + chunk * 4;  // freq index of first pair
  float cv[4], sv[4];
#pragma unroll
  for (int j = 0; j < 4; ++j) { cv[j] = cosT[fi + j]; sv[j] = sinT[fi + j]; }
  u16x4 q0 = *(u16x4*)(Qb + base), q1 = *(u16x4*)(Qb + base + 4);
  u16x4 k0 = *(u16x4*)(Kb + base), k1 = *(u16x4*)(Kb + base + 4);
  u16 qi[8] = {q0[0], q0[1], q0[2], q0[3], q1[0], q1[1], q1[2], q1[3]};
  u16 ki[8] = {k0[0], k0[1], k0[2], k0[3], k1[0], k1[1], k1[2], k1[3]};
  u16 qo[8], ko[8];
#pragma unroll
  for (int j = 0; j < 4; ++j) {
    float e = bf2f(qi[2 * j]), o = bf2f(qi[2 * j + 1]);
    qo[2 * j]     = f2bf((e * cv[j] - o * sv[j]) * QSCALE);
    qo[2 * j + 1] = f2bf((e * sv[j] + o * cv[j]) * QSCALE);
    e = bf2f(ki[2 * j]); o = bf2f(ki[2 * j + 1]);
    ko[2 * j]     = f2bf(e * cv[j] - o * sv[j]);
    ko[2 * j + 1] = f2bf(e * sv[j] + o * cv[j]);
  }
  u16x4 a{qo[0], qo[1], qo[2], qo[3]}, b{qo[4], qo[5], qo[6], qo[7]};
  u16x4 c{ko[0], ko[1], ko[2], ko[3]}, d{ko[4], ko[5], ko[6], ko[7]};
  *(u16x4*)(Qb + base) = a; *(u16x4*)(Qb + base + 4) = b;
  *(u16x4*)(Kb + base) = c; *(u16x4*)(Kb + base + 4) = d;
}

// ------------------------------------------------------------- flash attention
// SWAPPED operands: sacc[n] = mfma(K, Q) = S^T. Each lane owns ONE q-row
// (q = qbase + lr) and 16 kv values (n*16 + lg*4 + j). Softmax is lane-local
// + 2 shfls across the lg groups. PV computed as O^T = mfma(V^T, P^T):
// V^T A-frags load straight from Vt; P^T B-frags via a tiny per-wave LDS
// round trip (4x ds_write_b64 + 2x ds_read_b128, 16B-pair XOR swizzle).
template<bool MASKED>
static __device__ __forceinline__ void attn_tile(
    const u16* __restrict__ Kh, const u16* __restrict__ Vh,
    int kv0, int qrow, const bf16x8 (&qf)[2], u16 (*Ps)[64],
    f32x4 (&accO)[4], float& m, float& l, int lr, int lg) {
  f32x4 sacc[4] = {};
#pragma unroll
  for (int n = 0; n < 4; ++n)
#pragma unroll
    for (int kk = 0; kk < 2; ++kk) {
      bf16x8 kf = *(const bf16x8*)(Kh + (size_t)(kv0 + n * 16 + lr) * 64 + kk * 32 + lg * 8);
      sacc[n] = __builtin_amdgcn_mfma_f32_16x16x32_bf16(kf, qf[kk], sacc[n], 0, 0, 0);
    }
  if (MASKED) {
#pragma unroll
    for (int n = 0; n < 4; ++n)
#pragma unroll
      for (int j = 0; j < 4; ++j) {
        const int c = kv0 + n * 16 + lg * 4 + j;
        if (c > qrow) sacc[n][j] = -1e30f;
      }
  }
  float tm = fmaxf(fmaxf(fmaxf(sacc[0][0], sacc[0][1]), fmaxf(sacc[0][2], sacc[0][3])),
                   fmaxf(fmaxf(sacc[1][0], sacc[1][1]), fmaxf(sacc[1][2], sacc[1][3])));
  tm = fmaxf(tm, fmaxf(fmaxf(fmaxf(sacc[2][0], sacc[2][1]), fmaxf(sacc[2][2], sacc[2][3])),
                       fmaxf(fmaxf(sacc[3][0], sacc[3][1]), fmaxf(sacc[3][2], sacc[3][3]))));
  tm = fmaxf(tm, __shfl_xor(tm, 16));
  tm = fmaxf(tm, __shfl_xor(tm, 32));
  const float mn = fmaxf(m, tm);
  const float al = exp2f(m - mn);
  m = mn;
  float ssum = 0.f;
  u16x4 pk[4];
#pragma unroll
  for (int n = 0; n < 4; ++n)
#pragma unroll
    for (int j = 0; j < 4; ++j) {
      float p = exp2f(sacc[n][j] - mn);
      ssum += p;
      pk[n][j] = f2bf(p);
    }
  ssum += __shfl_xor(ssum, 16);
  ssum += __shfl_xor(ssum, 32);
  l = l * al + ssum;
#pragma unroll
  for (int n = 0; n < 4; ++n)
#pragma unroll
    for (int j = 0; j < 4; ++j)
      accO[n][j] *= al;
  // store P row (q = lr): 16B-pair position = pair ^ (lr&7); half = granule&1
#pragma unroll
  for (int n = 0; n < 4; ++n) {
    const int g = n * 4 + lg;
    const int off = ((((g >> 1) ^ (lr & 7)) << 3) | ((g & 1) << 2));
    *(u16x4*)&Ps[lr][off] = pk[n];
  }
#pragma unroll
  for (int kk = 0; kk < 2; ++kk) {
    const int po = (((kk * 4 + lg) ^ (lr & 7)) << 3);
    bf16x8 pb = *(const bf16x8*)&Ps[lr][po];   // P[q=lr][kv = kk*32+lg*8 ..+8]
#pragma unroll
    for (int db = 0; db < 4; ++db) {
      bf16x8 vf = *(const bf16x8*)(Vh + (size_t)(db * 16 + lr) * 2048 + kv0 + kk * 32 + lg * 8);
      accO[db] = __builtin_amdgcn_mfma_f32_16x16x32_bf16(vf, pb, accO[db], 0, 0, 0);
    }
  }
}

// grid (B*16 heads, 64 q-chunks heavy-first), 128 thr = 2 waves x 16 q-rows.
__global__ __launch_bounds__(128, 4)
void flash_attn_kernel(const u16* __restrict__ Q, const u16* __restrict__ K,
                       const u16* __restrict__ Vt, u16* __restrict__ O) {
  __shared__ __align__(16) u16 Ps[2][16][64];
  const int bh = blockIdx.x;
  const int qc = 63 - (int)blockIdx.y;     // heavy-first
  const int b = bh >> 4, h = bh & 15;
  const int tid = threadIdx.x;
  const int wave = tid >> 6, lane = tid & 63;
  const int lr = lane & 15, lg = lane >> 4;
  const int qbase = qc * 32 + wave * 16;
  const int qrow = qbase + lr;             // this lane's q-row
  const size_t hb = (size_t)bh * (2048 * 64);
  const u16* Qh = Q + hb;
  const u16* Kh = K + hb;
  const u16* Vh = Vt + hb;

  bf16x8 qf[2];
#pragma unroll
  for (int kk = 0; kk < 2; ++kk)
    qf[kk] = *(const bf16x8*)(Qh + (size_t)qrow * 64 + kk * 32 + lg * 8);

  f32x4 accO[4] = {};
  float m = -1e30f, l = 0.f;

  const int nfull = qbase >> 6;            // tiles fully below the diagonal
  for (int t = 0; t < nfull; ++t)
    attn_tile<false>(Kh, Vh, t * 64, qrow, qf, Ps[wave], accO, m, l, lr, lg);
  attn_tile<true>(Kh, Vh, nfull * 64, qrow, qf, Ps[wave], accO, m, l, lr, lg);

  const float inv = 1.0f / l;
#pragma unroll
  for (int db = 0; db < 4; ++db) {
    u16x4 pk;
#pragma unroll
    for (int j = 0; j < 4; ++j) pk[j] = f2bf(accO[db][j] * inv);
    const int d = db * 16 + lg * 4;
    *(u16x4*)&O[((size_t)(b * 2048 + qrow) * 16 + h) * 64 + d] = pk;
  }
}

// ------------------------------------------------------------ output projection
template<bool WF32>
__global__ __launch_bounds__(256, 2)
void out_gemm_kernel(const u16* __restrict__ A, const void* __restrict__ W,
                     float* __restrict__ out) {
  __shared__ __align__(16) u16 As[128 * 32];
  __shared__ __align__(16) u16 Bs[128 * 32];
  const int m0 = blockIdx.x * 128, n0 = blockIdx.y * 128;
  f32x4 acc[4][4] = {};
  gemm128_core<false, WF32>(A, W, As, Bs, m0, n0, acc);
  const int lane = threadIdx.x & 63, wave = threadIdx.x >> 6;
  const int wr = (wave >> 1) * 64, wc = (wave & 1) * 64;
  const int lr = lane & 15, lg = lane >> 4;
#pragma unroll
  for (int i = 0; i < 4; ++i)
#pragma unroll
    for (int n = 0; n < 4; ++n) {
      const int c = n0 + wc + n * 16 + lr;
#pragma unroll
      for (int j = 0; j < 4; ++j) {
        const int r = m0 + wr + i * 16 + lg * 4 + j;
        out[(size_t)r * 1024 + c] = acc[i][n][j];   // f32 store, no rounding
      }
    }
}

// --------------------------------------------------------------------- launch
extern "C" void kernel_launch(void* const* d_in, const int* in_sizes, int n_in,
                              void* d_out, int out_size, void* d_ws, size_t ws_size,
                              hipStream_t stream) {
  const float* x  = (const float*)d_in[0];
  const int*   tp = (const int*)d_in[1];
  const float* Wq = (const float*)d_in[2];
  const float* Wk = (const float*)d_in[3];
  const float* Wv = (const float*)d_in[4];
  const float* Wo = (const float*)d_in[5];
  float* out = (float*)d_out;
  const int B = in_sizes[0] / (2048 * 1024);
  const size_t xel = (size_t)B * 2048 * 1024;        // X elements
  const size_t tsz = xel * sizeof(u16);              // 8MB @ B=2
  const size_t TBL = 2048 * 32 * 2 * sizeof(float);  // cos+sin tables
  // Q,K (bf16) live inside d_out (f32 out = 2*tsz bytes); consumed by flash
  // before out_gemm overwrites. Vt, Ob, tables (+ optional bf16 copies) in ws.
  u16* Qb = (u16*)d_out;
  u16* Kb = (u16*)((char*)d_out + tsz);
  char* ws = (char*)d_ws;
  u16* Vt = (u16*)(ws);
  u16* Ob = (u16*)(ws + tsz);
  float* cosT = (float*)(ws + 2 * tsz);
  float* sinT = cosT + 2048 * 32;
  u16* Xb  = (u16*)(ws + 2 * tsz + TBL);
  u16* Wqb = Xb + xel;
  u16* Wkb = Wqb + 1024 * 1024;
  u16* Wvb = Wkb + 1024 * 1024;
  u16* Wob = Wvb + 1024 * 1024;
  const size_t need = 2 * tsz + TBL + tsz + 4 * (size_t)(1024 * 1024) * sizeof(u16);
  const bool cvt = ws_size >= need;

  rope_tables_kernel<<<dim3(256), dim3(256), 0, stream>>>(tp, cosT, sinT);
  if (cvt) {
    cvt_bf16_kernel<<<dim3((int)(xel / 8 / 256)), dim3(256), 0, stream>>>(x, Xb, (int)(xel / 8));
    cvt_bf16_kernel<<<dim3(512), dim3(256), 0, stream>>>(Wq, Wqb, 1024 * 1024 / 8);
    cvt_bf16_kernel<<<dim3(512), dim3(256), 0, stream>>>(Wk, Wkb, 1024 * 1024 / 8);
    cvt_bf16_kernel<<<dim3(512), dim3(256), 0, stream>>>(Wv, Wvb, 1024 * 1024 / 8);
    cvt_bf16_kernel<<<dim3(512), dim3(256), 0, stream>>>(Wo, Wob, 1024 * 1024 / 8);
    qkv_gemm_kernel<false><<<dim3(B * 16, 8, 3), dim3(256), 0, stream>>>(
        Xb, Wqb, Wkb, Wvb, Qb, Kb, Vt);
  } else {
    qkv_gemm_kernel<true><<<dim3(B * 16, 8, 3), dim3(256), 0, stream>>>(
        x, Wq, Wk, Wv, Qb, Kb, Vt);
  }
  rope_apply_kernel<<<dim3(B * 16 * 2048 * 8 / 256), dim3(256), 0, stream>>>(
      Qb, Kb, cosT, sinT, B * 16 * 2048 * 8);
  flash_attn_kernel<<<dim3(B * 16, 64), dim3(128), 0, stream>>>(Qb, Kb, Vt, Ob);
  if (cvt) {
    out_gemm_kernel<false><<<dim3(B * 16, 8), dim3(256), 0, stream>>>(Ob, Wob, out);
  } else {
    out_gemm_kernel<true><<<dim3(B * 16, 8), dim3(256), 0, stream>>>(Ob, Wo, out);
  }
}

// Round 6
// 135.587 us; speedup vs baseline: 2.1883x; 1.5768x over previous
//
#include <hip/hip_runtime.h>
#include <stdint.h>

// CausalMultiHeadSelfAttention: B=2, S=2048, D_MODEL=1024, H=16, DK=64
// I/O: f32 (+ int32 positions). Internal: bf16 MFMA, f32 accum.
// Pipeline: rope tables -> [bf16 pre-convert of X,W*] -> QKV gemm (V^T out) ->
//           rope(Q,K; Q scaled 0.125*log2e) -> causal flash attn (block=4
//           waves sharing LDS-staged K/V tiles, swapped QK^T, lane-local
//           softmax) -> out gemm (f32 out).
// Q,K live in d_out (consumed by flash before out_gemm overwrites).

typedef unsigned short u16;
typedef __bf16 bf16x8 __attribute__((ext_vector_type(8)));
typedef float f32x4 __attribute__((ext_vector_type(4)));
typedef u16 u16x4 __attribute__((ext_vector_type(4)));

#define LOG2E 1.44269504088896340736f
#define QSCALE (0.125f * LOG2E)   // folded into Q at rope time

static __device__ __forceinline__ u16 f2bf(float f) {
  union { float f; uint32_t u; } v; v.f = f;
  uint32_t u = v.u;
  return (u16)((u + 0x7FFFu + ((u >> 16) & 1u)) >> 16);  // RNE
}
static __device__ __forceinline__ float bf2f(u16 h) {
  union { uint32_t u; float f; } v; v.u = ((uint32_t)h) << 16; return v.f;
}

template<bool F32>
static __device__ __forceinline__ bf16x8 load8(const void* p, size_t off) {
  if constexpr (F32) {
    const float* f = (const float*)p + off;
    f32x4 a = *(const f32x4*)f;
    f32x4 b = *(const f32x4*)(f + 4);
    bf16x8 r;
    r[0] = (__bf16)a[0]; r[1] = (__bf16)a[1]; r[2] = (__bf16)a[2]; r[3] = (__bf16)a[3];
    r[4] = (__bf16)b[0]; r[5] = (__bf16)b[1]; r[6] = (__bf16)b[2]; r[7] = (__bf16)b[3];
    return r;
  } else {
    return *(const bf16x8*)((const u16*)p + off);
  }
}

// async global(16B/lane) -> LDS; dest must be wave-uniform base + lane*16.
static __device__ __forceinline__ void glds16(const u16* g, u16* l) {
  __builtin_amdgcn_global_load_lds(
      (const __attribute__((address_space(1))) unsigned int*)g,
      (__attribute__((address_space(3))) unsigned int*)l, 16, 0, 0);
}

// ---------------------------------------------------------------- rope tables
__global__ void rope_tables_kernel(const int* __restrict__ tp,
                                   float* __restrict__ cosT, float* __restrict__ sinT) {
  int idx = blockIdx.x * 256 + threadIdx.x;          // 2048*32
  if (idx >= 2048 * 32) return;
  int s = idx >> 5, i = idx & 31;
  float p = (float)tp[s];
  float freq = powf(10000.0f, -(float)i / 32.0f);    // theta^(-2i/64)
  float ang = p * freq;
  cosT[idx] = cosf(ang);
  sinT[idx] = sinf(ang);
}

// ------------------------------------------------------------- f32 -> bf16
__global__ void cvt_bf16_kernel(const float* __restrict__ in,
                                u16* __restrict__ out, int n8) {
  int i = blockIdx.x * 256 + threadIdx.x;
  if (i >= n8) return;
  const float* p = in + (size_t)i * 8;
  f32x4 a = *(const f32x4*)p;
  f32x4 b = *(const f32x4*)(p + 4);
  bf16x8 r;
  r[0] = (__bf16)a[0]; r[1] = (__bf16)a[1]; r[2] = (__bf16)a[2]; r[3] = (__bf16)a[3];
  r[4] = (__bf16)b[0]; r[5] = (__bf16)b[1]; r[6] = (__bf16)b[2]; r[7] = (__bf16)b[3];
  *(bf16x8*)(out + (size_t)i * 8) = r;
}

// ------------------------------------------------------------- 128x128 gemm core
// Both bf16 (AF32=BF32=false): async global_load_lds staging.
// Else: reg-staged with inline f32->bf16 conversion.
template<bool AF32, bool BF32>
static __device__ __forceinline__ void gemm128_core(
    const void* __restrict__ A, const void* __restrict__ W,
    u16* As, u16* Bs, int m0, int n0, f32x4 (&acc)[4][4]) {
  const int tid = threadIdx.x;
  const int lane = tid & 63;
  const int wave = tid >> 6;
  const int wr = (wave >> 1) * 64, wc = (wave & 1) * 64;
  const int lr = lane & 15, lg = lane >> 4;
  const int srow = tid >> 2;            // 0..63
  const int scol = (tid & 3) * 8;       // k element offset
  for (int k0 = 0; k0 < 1024; k0 += 32) {
    if constexpr (!AF32 && !BF32) {
      const u16* Ab = (const u16*)A;
      const u16* Wb = (const u16*)W;
      __syncthreads();   // previous iteration's LDS reads done
      glds16(Ab + (size_t)(m0 + srow) * 1024 + k0 + scol, As + tid * 8);
      glds16(Ab + (size_t)(m0 + 64 + srow) * 1024 + k0 + scol, As + 2048 + tid * 8);
      glds16(Wb + (size_t)(n0 + srow) * 1024 + k0 + scol, Bs + tid * 8);
      glds16(Wb + (size_t)(n0 + 64 + srow) * 1024 + k0 + scol, Bs + 2048 + tid * 8);
      __syncthreads();   // vmcnt(0) drained before barrier -> data visible
    } else {
      bf16x8 ta0 = load8<AF32>(A, (size_t)(m0 + srow) * 1024 + k0 + scol);
      bf16x8 ta1 = load8<AF32>(A, (size_t)(m0 + 64 + srow) * 1024 + k0 + scol);
      bf16x8 tb0 = load8<BF32>(W, (size_t)(n0 + srow) * 1024 + k0 + scol);
      bf16x8 tb1 = load8<BF32>(W, (size_t)(n0 + 64 + srow) * 1024 + k0 + scol);
      __syncthreads();
      *(bf16x8*)(As + tid * 8)        = ta0;
      *(bf16x8*)(As + 2048 + tid * 8) = ta1;
      *(bf16x8*)(Bs + tid * 8)        = tb0;
      *(bf16x8*)(Bs + 2048 + tid * 8) = tb1;
      __syncthreads();
    }
    bf16x8 af[4], bfr[4];
#pragma unroll
    for (int i = 0; i < 4; ++i) {
      af[i]  = *(const bf16x8*)(As + (wr + i * 16 + lr) * 32 + lg * 8);
      bfr[i] = *(const bf16x8*)(Bs + (wc + i * 16 + lr) * 32 + lg * 8);
    }
#pragma unroll
    for (int i = 0; i < 4; ++i)
#pragma unroll
      for (int j = 0; j < 4; ++j)
        acc[i][j] = __builtin_amdgcn_mfma_f32_16x16x32_bf16(af[i], bfr[j], acc[i][j], 0, 0, 0);
  }
}

// ------------------------------------------------------------------ QKV gemm
// z=0: Q -> (B,H,S,64); z=1: K -> (B,H,S,64); z=2: V -> (B,H,64,S) transposed.
template<bool F32>
__global__ __launch_bounds__(256, 2)
void qkv_gemm_kernel(const void* __restrict__ X,
                     const void* __restrict__ Wq, const void* __restrict__ Wk,
                     const void* __restrict__ Wv,
                     u16* __restrict__ Qo, u16* __restrict__ Ko, u16* __restrict__ Vto) {
  __shared__ __align__(16) u16 As[128 * 32];
  __shared__ __align__(16) u16 Bs[128 * 32];
  const int z = blockIdx.z;
  const void* W = (z == 0) ? Wq : ((z == 1) ? Wk : Wv);
  const int m0 = blockIdx.x * 128, n0 = blockIdx.y * 128;
  f32x4 acc[4][4] = {};
  gemm128_core<F32, F32>(X, W, As, Bs, m0, n0, acc);
  const int lane = threadIdx.x & 63, wave = threadIdx.x >> 6;
  const int wr = (wave >> 1) * 64, wc = (wave & 1) * 64;
  const int lr = lane & 15, lg = lane >> 4;
  if (z < 2) {
    u16* dst = z ? Ko : Qo;
#pragma unroll
    for (int i = 0; i < 4; ++i) {
      const int rb = m0 + wr + i * 16 + lg * 4;  // global row = b*2048+s
#pragma unroll
      for (int n = 0; n < 4; ++n) {
        const int c = n0 + wc + n * 16 + lr;     // feature -> h,d
        const int hh = c >> 6, d = c & 63;
#pragma unroll
        for (int j = 0; j < 4; ++j) {
          const int r = rb + j;
          dst[(((size_t)(r >> 11) * 16 + hh) * 2048 + (r & 2047)) * 64 + d] =
              f2bf(acc[i][n][j]);
        }
      }
    }
  } else {  // V transposed: 4 consecutive rows (j) pack into one 8B store
#pragma unroll
    for (int i = 0; i < 4; ++i) {
      const int s0 = m0 + wr + i * 16 + lg * 4;
      const int bb = s0 >> 11, ss = s0 & 2047;
#pragma unroll
      for (int n = 0; n < 4; ++n) {
        const int c = n0 + wc + n * 16 + lr;
        const int hh = c >> 6, d = c & 63;
        u16x4 pk;
#pragma unroll
        for (int j = 0; j < 4; ++j) pk[j] = f2bf(acc[i][n][j]);
        *(u16x4*)(Vto + (((size_t)bb * 16 + hh) * 64 + d) * 2048 + ss) = pk;
      }
    }
  }
}

// ------------------------------------------------------------------ RoPE apply
// Q additionally scaled by QSCALE (attention scale + exp->exp2 fold).
__global__ void rope_apply_kernel(u16* __restrict__ Qb, u16* __restrict__ Kb,
                                  const float* __restrict__ cosT,
                                  const float* __restrict__ sinT, int total) {
  int g = blockIdx.x * 256 + threadIdx.x;
  if (g >= total) return;
  int chunk = g & 7;            // which 8-elem group within d=64
  int s = (g >> 3) & 2047;
  size_t base = (size_t)g * 8;
  int fi = s * 32 + chunk * 4;  // freq index of first pair
  float cv[4], sv[4];
#pragma unroll
  for (int j = 0; j < 4; ++j) { cv[j] = cosT[fi + j]; sv[j] = sinT[fi + j]; }
  u16x4 q0 = *(u16x4*)(Qb + base), q1 = *(u16x4*)(Qb + base + 4);
  u16x4 k0 = *(u16x4*)(Kb + base), k1 = *(u16x4*)(Kb + base + 4);
  u16 qi[8] = {q0[0], q0[1], q0[2], q0[3], q1[0], q1[1], q1[2], q1[3]};
  u16 ki[8] = {k0[0], k0[1], k0[2], k0[3], k1[0], k1[1], k1[2], k1[3]};
  u16 qo[8], ko[8];
#pragma unroll
  for (int j = 0; j < 4; ++j) {
    float e = bf2f(qi[2 * j]), o = bf2f(qi[2 * j + 1]);
    qo[2 * j]     = f2bf((e * cv[j] - o * sv[j]) * QSCALE);
    qo[2 * j + 1] = f2bf((e * sv[j] + o * cv[j]) * QSCALE);
    e = bf2f(ki[2 * j]); o = bf2f(ki[2 * j + 1]);
    ko[2 * j]     = f2bf(e * cv[j] - o * sv[j]);
    ko[2 * j + 1] = f2bf(e * sv[j] + o * cv[j]);
  }
  u16x4 a{qo[0], qo[1], qo[2], qo[3]}, b{qo[4], qo[5], qo[6], qo[7]};
  u16x4 c{ko[0], ko[1], ko[2], ko[3]}, d{ko[4], ko[5], ko[6], ko[7]};
  *(u16x4*)(Qb + base) = a; *(u16x4*)(Qb + base + 4) = b;
  *(u16x4*)(Kb + base) = c; *(u16x4*)(Kb + base + 4) = d;
}

// ------------------------------------------------------------- flash attention
// Block = 4 waves x 16 q-rows = one 64-row diagonal band. K and V^T tiles
// (64x64 bf16 = 8KB each) are double-buffered in LDS via global_load_lds,
// shared by all 4 waves (4x L2 traffic reduction vs per-wave streaming).
// All waves have identical trip count nt = qcb+1; only the last tile is
// masked. LDS granule-XOR swizzle: LDS[row][g] = G[row][g ^ (row&7)]
// (16B granules) -- staging pre-swizzles the GLOBAL source address (each
// 8-lane group still covers one full 128B line), reads un-swizzle.
// Swapped QK^T: sacc = mfma(K,Q) = S^T; lane owns one q-row; softmax is
// lane-local + 2 shfls. PV as O^T = mfma(V^T, P^T) with P via per-wave LDS.
template<bool MASKED>
static __device__ __forceinline__ void attn_tile(
    const u16* kb, const u16* vb, int kv0, int qrow,
    const bf16x8 (&qf)[2], u16* Psw,
    f32x4 (&accO)[4], float& m, float& l, int lr, int lg) {
  f32x4 sacc[4] = {};
#pragma unroll
  for (int n = 0; n < 4; ++n)
#pragma unroll
    for (int kk = 0; kk < 2; ++kk) {
      const int gsw = ((((kk << 2) | lg) ^ (lr & 7)) << 3);
      bf16x8 kf = *(const bf16x8*)&kb[(n * 16 + lr) * 64 + gsw];
      sacc[n] = __builtin_amdgcn_mfma_f32_16x16x32_bf16(kf, qf[kk], sacc[n], 0, 0, 0);
    }
  if (MASKED) {
#pragma unroll
    for (int n = 0; n < 4; ++n)
#pragma unroll
      for (int j = 0; j < 4; ++j) {
        const int c = kv0 + n * 16 + lg * 4 + j;
        if (c > qrow) sacc[n][j] = -1e30f;
      }
  }
  float tm = fmaxf(fmaxf(fmaxf(sacc[0][0], sacc[0][1]), fmaxf(sacc[0][2], sacc[0][3])),
                   fmaxf(fmaxf(sacc[1][0], sacc[1][1]), fmaxf(sacc[1][2], sacc[1][3])));
  tm = fmaxf(tm, fmaxf(fmaxf(fmaxf(sacc[2][0], sacc[2][1]), fmaxf(sacc[2][2], sacc[2][3])),
                       fmaxf(fmaxf(sacc[3][0], sacc[3][1]), fmaxf(sacc[3][2], sacc[3][3]))));
  tm = fmaxf(tm, __shfl_xor(tm, 16));
  tm = fmaxf(tm, __shfl_xor(tm, 32));
  const float mn = fmaxf(m, tm);
  const float al = exp2f(m - mn);
  m = mn;
  float ssum = 0.f;
  u16x4 pk[4];
#pragma unroll
  for (int n = 0; n < 4; ++n)
#pragma unroll
    for (int j = 0; j < 4; ++j) {
      float p = exp2f(sacc[n][j] - mn);
      ssum += p;
      pk[n][j] = f2bf(p);
    }
  ssum += __shfl_xor(ssum, 16);
  ssum += __shfl_xor(ssum, 32);
  l = l * al + ssum;
#pragma unroll
  for (int n = 0; n < 4; ++n)
#pragma unroll
    for (int j = 0; j < 4; ++j)
      accO[n][j] *= al;
  // store P row (q = lr): 16B-pair position = pair ^ (lr&7); half = granule&1
#pragma unroll
  for (int n = 0; n < 4; ++n) {
    const int g = n * 4 + lg;
    const int off = ((((g >> 1) ^ (lr & 7)) << 3) | ((g & 1) << 2));
    *(u16x4*)&Psw[lr * 64 + off] = pk[n];
  }
#pragma unroll
  for (int kk = 0; kk < 2; ++kk) {
    const int po = (((kk * 4 + lg) ^ (lr & 7)) << 3);
    bf16x8 pb = *(const bf16x8*)&Psw[lr * 64 + po];  // P[q=lr][kk*32+lg*8..+8]
#pragma unroll
    for (int db = 0; db < 4; ++db) {
      const int gsw = ((((kk << 2) | lg) ^ (lr & 7)) << 3);
      bf16x8 vf = *(const bf16x8*)&vb[(db * 16 + lr) * 64 + gsw];
      accO[db] = __builtin_amdgcn_mfma_f32_16x16x32_bf16(vf, pb, accO[db], 0, 0, 0);
    }
  }
}

// grid (B*16 heads, 32 bands heavy-first), 256 thr = 4 waves x 16 q-rows.
__global__ __launch_bounds__(256, 4)
void flash_attn_kernel(const u16* __restrict__ Q, const u16* __restrict__ K,
                       const u16* __restrict__ Vt, u16* __restrict__ O) {
  __shared__ __align__(16) u16 Klds[2][64 * 64];
  __shared__ __align__(16) u16 Vlds[2][64 * 64];
  __shared__ __align__(16) u16 Ps[4][16 * 64];
  const int bh = blockIdx.x;
  const int qcb = 31 - (int)blockIdx.y;    // heavy-first
  const int b = bh >> 4, h = bh & 15;
  const int tid = threadIdx.x;
  const int wv = tid >> 6, lane = tid & 63;
  const int lr = lane & 15, lg = lane >> 4;
  const int qbase = qcb * 64 + wv * 16;
  const int qrow = qbase + lr;             // this lane's q-row
  const size_t hb = (size_t)bh * (2048 * 64);
  const u16* Qh = Q + hb;
  const u16* Kh = K + hb;
  const u16* Vh = Vt + hb;

  // staging: lane l covers row (l>>3) of its 8-row group, source granule
  // pre-swizzled so LDS stays linear while holding swizzled content.
  const int sgr = ((lane & 7) ^ (lane >> 3)) << 3;  // src elem offset in row
  const int srw = lane >> 3;                        // 0..7
  auto STAGE = [&](int kv0, int bufi) {
    u16* kbd = Klds[bufi];
    u16* vbd = Vlds[bufi];
#pragma unroll
    for (int i = 0; i < 2; ++i) {
      const int r = wv * 16 + i * 8;
      glds16(Kh + (size_t)(kv0 + r + srw) * 64 + sgr, kbd + r * 64);
      glds16(Vh + (size_t)(r + srw) * 2048 + kv0 + sgr, vbd + r * 64);
    }
  };

  bf16x8 qf[2];
#pragma unroll
  for (int kk = 0; kk < 2; ++kk)
    qf[kk] = *(const bf16x8*)(Qh + (size_t)qrow * 64 + kk * 32 + lg * 8);

  f32x4 accO[4] = {};
  float m = -1e30f, l = 0.f;

  const int nt = qcb + 1;                  // tiles incl. the masked diagonal
  STAGE(0, 0);
  __syncthreads();                         // drain stage-0, all waves ready
  for (int t = 0; t < nt - 1; ++t) {
    STAGE((t + 1) * 64, (t & 1) ^ 1);      // prefetch next into other buffer
    attn_tile<false>(Klds[t & 1], Vlds[t & 1], t * 64, qrow, qf, Ps[wv],
                     accO, m, l, lr, lg);
    __syncthreads();                       // drain prefetch + lds reads
  }
  attn_tile<true>(Klds[(nt - 1) & 1], Vlds[(nt - 1) & 1], (nt - 1) * 64, qrow,
                  qf, Ps[wv], accO, m, l, lr, lg);

  const float inv = 1.0f / l;
#pragma unroll
  for (int db = 0; db < 4; ++db) {
    u16x4 pk;
#pragma unroll
    for (int j = 0; j < 4; ++j) pk[j] = f2bf(accO[db][j] * inv);
    const int d = db * 16 + lg * 4;
    *(u16x4*)&O[((size_t)(b * 2048 + qrow) * 16 + h) * 64 + d] = pk;
  }
}

// ------------------------------------------------------------ output projection
template<bool WF32>
__global__ __launch_bounds__(256, 2)
void out_gemm_kernel(const u16* __restrict__ A, const void* __restrict__ W,
                     float* __restrict__ out) {
  __shared__ __align__(16) u16 As[128 * 32];
  __shared__ __align__(16) u16 Bs[128 * 32];
  const int m0 = blockIdx.x * 128, n0 = blockIdx.y * 128;
  f32x4 acc[4][4] = {};
  gemm128_core<false, WF32>(A, W, As, Bs, m0, n0, acc);
  const int lane = threadIdx.x & 63, wave = threadIdx.x >> 6;
  const int wr = (wave >> 1) * 64, wc = (wave & 1) * 64;
  const int lr = lane & 15, lg = lane >> 4;
#pragma unroll
  for (int i = 0; i < 4; ++i)
#pragma unroll
    for (int n = 0; n < 4; ++n) {
      const int c = n0 + wc + n * 16 + lr;
#pragma unroll
      for (int j = 0; j < 4; ++j) {
        const int r = m0 + wr + i * 16 + lg * 4 + j;
        out[(size_t)r * 1024 + c] = acc[i][n][j];   // f32 store, no rounding
      }
    }
}

// --------------------------------------------------------------------- launch
extern "C" void kernel_launch(void* const* d_in, const int* in_sizes, int n_in,
                              void* d_out, int out_size, void* d_ws, size_t ws_size,
                              hipStream_t stream) {
  const float* x  = (const float*)d_in[0];
  const int*   tp = (const int*)d_in[1];
  const float* Wq = (const float*)d_in[2];
  const float* Wk = (const float*)d_in[3];
  const float* Wv = (const float*)d_in[4];
  const float* Wo = (const float*)d_in[5];
  float* out = (float*)d_out;
  const int B = in_sizes[0] / (2048 * 1024);
  const size_t xel = (size_t)B * 2048 * 1024;        // X elements
  const size_t tsz = xel * sizeof(u16);              // 8MB @ B=2
  const size_t TBL = 2048 * 32 * 2 * sizeof(float);  // cos+sin tables
  // Q,K (bf16) live inside d_out (f32 out = 2*tsz bytes); consumed by flash
  // before out_gemm overwrites. Vt, Ob, tables (+ optional bf16 copies) in ws.
  u16* Qb = (u16*)d_out;
  u16* Kb = (u16*)((char*)d_out + tsz);
  char* ws = (char*)d_ws;
  u16* Vt = (u16*)(ws);
  u16* Ob = (u16*)(ws + tsz);
  float* cosT = (float*)(ws + 2 * tsz);
  float* sinT = cosT + 2048 * 32;
  u16* Xb  = (u16*)(ws + 2 * tsz + TBL);
  u16* Wqb = Xb + xel;
  u16* Wkb = Wqb + 1024 * 1024;
  u16* Wvb = Wkb + 1024 * 1024;
  u16* Wob = Wvb + 1024 * 1024;
  const size_t need = 2 * tsz + TBL + tsz + 4 * (size_t)(1024 * 1024) * sizeof(u16);
  const bool cvt = ws_size >= need;

  rope_tables_kernel<<<dim3(256), dim3(256), 0, stream>>>(tp, cosT, sinT);
  if (cvt) {
    cvt_bf16_kernel<<<dim3((int)(xel / 8 / 256)), dim3(256), 0, stream>>>(x, Xb, (int)(xel / 8));
    cvt_bf16_kernel<<<dim3(512), dim3(256), 0, stream>>>(Wq, Wqb, 1024 * 1024 / 8);
    cvt_bf16_kernel<<<dim3(512), dim3(256), 0, stream>>>(Wk, Wkb, 1024 * 1024 / 8);
    cvt_bf16_kernel<<<dim3(512), dim3(256), 0, stream>>>(Wv, Wvb, 1024 * 1024 / 8);
    cvt_bf16_kernel<<<dim3(512), dim3(256), 0, stream>>>(Wo, Wob, 1024 * 1024 / 8);
    qkv_gemm_kernel<false><<<dim3(B * 16, 8, 3), dim3(256), 0, stream>>>(
        Xb, Wqb, Wkb, Wvb, Qb, Kb, Vt);
  } else {
    qkv_gemm_kernel<true><<<dim3(B * 16, 8, 3), dim3(256), 0, stream>>>(
        x, Wq, Wk, Wv, Qb, Kb, Vt);
  }
  rope_apply_kernel<<<dim3(B * 16 * 2048 * 8 / 256), dim3(256), 0, stream>>>(
      Qb, Kb, cosT, sinT, B * 16 * 2048 * 8);
  flash_attn_kernel<<<dim3(B * 16, 32), dim3(256), 0, stream>>>(Qb, Kb, Vt, Ob);
  if (cvt) {
    out_gemm_kernel<false><<<dim3(B * 16, 8), dim3(256), 0, stream>>>(Ob, Wob, out);
  } else {
    out_gemm_kernel<true><<<dim3(B * 16, 8), dim3(256), 0, stream>>>(Ob, Wo, out);
  }
}

// Round 7
// 120.410 us; speedup vs baseline: 2.4641x; 1.1260x over previous
//
#include <hip/hip_runtime.h>
#include <stdint.h>

// CausalMultiHeadSelfAttention: B=2, S=2048, D_MODEL=1024, H=16, DK=64
// I/O: f32 (+ int32 positions). Internal: bf16 MFMA, f32 accum.
// Pipeline: rope tables -> bf16 pre-convert (X, W*) -> QKV gemm with RoPE
//           fused into the epilogue (V^T out; Q scaled 0.125*log2e) ->
//           causal flash attn (LDS-shared K/V tiles, swapped QK^T,
//           lane-local softmax, defer-max) -> out gemm (f32 out).
// Q,K live in d_out (consumed by flash before out_gemm overwrites).

typedef unsigned short u16;
typedef __bf16 bf16x8 __attribute__((ext_vector_type(8)));
typedef float f32x4 __attribute__((ext_vector_type(4)));
typedef u16 u16x4 __attribute__((ext_vector_type(4)));

#define LOG2E 1.44269504088896340736f
#define QSCALE (0.125f * LOG2E)   // folded into Q at the gemm epilogue

// native cast -> v_cvt_pk_bf16_f32 (RNE), much cheaper than manual RNE
static __device__ __forceinline__ u16 f2bf(float f) {
  __bf16 b = (__bf16)f;
  return __builtin_bit_cast(u16, b);
}

template<bool F32>
static __device__ __forceinline__ bf16x8 load8(const void* p, size_t off) {
  if constexpr (F32) {
    const float* f = (const float*)p + off;
    f32x4 a = *(const f32x4*)f;
    f32x4 b = *(const f32x4*)(f + 4);
    bf16x8 r;
    r[0] = (__bf16)a[0]; r[1] = (__bf16)a[1]; r[2] = (__bf16)a[2]; r[3] = (__bf16)a[3];
    r[4] = (__bf16)b[0]; r[5] = (__bf16)b[1]; r[6] = (__bf16)b[2]; r[7] = (__bf16)b[3];
    return r;
  } else {
    return *(const bf16x8*)((const u16*)p + off);
  }
}

// async global(16B/lane) -> LDS; dest must be wave-uniform base + lane*16.
static __device__ __forceinline__ void glds16(const u16* g, u16* l) {
  __builtin_amdgcn_global_load_lds(
      (const __attribute__((address_space(1))) unsigned int*)g,
      (__attribute__((address_space(3))) unsigned int*)l, 16, 0, 0);
}

// ---------------------------------------------------------------- rope tables
__global__ void rope_tables_kernel(const int* __restrict__ tp,
                                   float* __restrict__ cosT, float* __restrict__ sinT) {
  int idx = blockIdx.x * 256 + threadIdx.x;          // 2048*32
  if (idx >= 2048 * 32) return;
  int s = idx >> 5, i = idx & 31;
  float p = (float)tp[s];
  float freq = powf(10000.0f, -(float)i / 32.0f);    // theta^(-2i/64)
  float ang = p * freq;
  cosT[idx] = cosf(ang);
  sinT[idx] = sinf(ang);
}

// ------------------------------------------------------------- f32 -> bf16
__global__ void cvt_bf16_kernel(const float* __restrict__ in,
                                u16* __restrict__ out, int n8) {
  int i = blockIdx.x * 256 + threadIdx.x;
  if (i >= n8) return;
  const float* p = in + (size_t)i * 8;
  f32x4 a = *(const f32x4*)p;
  f32x4 b = *(const f32x4*)(p + 4);
  bf16x8 r;
  r[0] = (__bf16)a[0]; r[1] = (__bf16)a[1]; r[2] = (__bf16)a[2]; r[3] = (__bf16)a[3];
  r[4] = (__bf16)b[0]; r[5] = (__bf16)b[1]; r[6] = (__bf16)b[2]; r[7] = (__bf16)b[3];
  *(bf16x8*)(out + (size_t)i * 8) = r;
}

// all 4 weight matrices in one launch (z selects)
__global__ void cvt_w_kernel(const float* __restrict__ Wq, const float* __restrict__ Wk,
                             const float* __restrict__ Wv, const float* __restrict__ Wo,
                             u16* __restrict__ out) {
  const int z = blockIdx.z;
  const float* src = (z == 0) ? Wq : (z == 1) ? Wk : (z == 2) ? Wv : Wo;
  u16* dst = out + (size_t)z * 1024 * 1024;
  int i = blockIdx.x * 256 + threadIdx.x;            // 512 blocks x 256
  const float* p = src + (size_t)i * 8;
  f32x4 a = *(const f32x4*)p;
  f32x4 b = *(const f32x4*)(p + 4);
  bf16x8 r;
  r[0] = (__bf16)a[0]; r[1] = (__bf16)a[1]; r[2] = (__bf16)a[2]; r[3] = (__bf16)a[3];
  r[4] = (__bf16)b[0]; r[5] = (__bf16)b[1]; r[6] = (__bf16)b[2]; r[7] = (__bf16)b[3];
  *(bf16x8*)(dst + (size_t)i * 8) = r;
}

// ------------------------------------------------------------- 128x128 gemm core
template<bool AF32, bool BF32>
static __device__ __forceinline__ void gemm128_core(
    const void* __restrict__ A, const void* __restrict__ W,
    u16* As, u16* Bs, int m0, int n0, f32x4 (&acc)[4][4]) {
  const int tid = threadIdx.x;
  const int lane = tid & 63;
  const int wave = tid >> 6;
  const int wr = (wave >> 1) * 64, wc = (wave & 1) * 64;
  const int lr = lane & 15, lg = lane >> 4;
  const int srow = tid >> 2;            // 0..63
  const int scol = (tid & 3) * 8;       // k element offset
  for (int k0 = 0; k0 < 1024; k0 += 32) {
    if constexpr (!AF32 && !BF32) {
      const u16* Ab = (const u16*)A;
      const u16* Wb = (const u16*)W;
      __syncthreads();   // previous iteration's LDS reads done
      glds16(Ab + (size_t)(m0 + srow) * 1024 + k0 + scol, As + tid * 8);
      glds16(Ab + (size_t)(m0 + 64 + srow) * 1024 + k0 + scol, As + 2048 + tid * 8);
      glds16(Wb + (size_t)(n0 + srow) * 1024 + k0 + scol, Bs + tid * 8);
      glds16(Wb + (size_t)(n0 + 64 + srow) * 1024 + k0 + scol, Bs + 2048 + tid * 8);
      __syncthreads();   // vmcnt(0) drained before barrier -> data visible
    } else {
      bf16x8 ta0 = load8<AF32>(A, (size_t)(m0 + srow) * 1024 + k0 + scol);
      bf16x8 ta1 = load8<AF32>(A, (size_t)(m0 + 64 + srow) * 1024 + k0 + scol);
      bf16x8 tb0 = load8<BF32>(W, (size_t)(n0 + srow) * 1024 + k0 + scol);
      bf16x8 tb1 = load8<BF32>(W, (size_t)(n0 + 64 + srow) * 1024 + k0 + scol);
      __syncthreads();
      *(bf16x8*)(As + tid * 8)        = ta0;
      *(bf16x8*)(As + 2048 + tid * 8) = ta1;
      *(bf16x8*)(Bs + tid * 8)        = tb0;
      *(bf16x8*)(Bs + 2048 + tid * 8) = tb1;
      __syncthreads();
    }
    bf16x8 af[4], bfr[4];
#pragma unroll
    for (int i = 0; i < 4; ++i) {
      af[i]  = *(const bf16x8*)(As + (wr + i * 16 + lr) * 32 + lg * 8);
      bfr[i] = *(const bf16x8*)(Bs + (wc + i * 16 + lr) * 32 + lg * 8);
    }
#pragma unroll
    for (int i = 0; i < 4; ++i)
#pragma unroll
      for (int j = 0; j < 4; ++j)
        acc[i][j] = __builtin_amdgcn_mfma_f32_16x16x32_bf16(af[i], bfr[j], acc[i][j], 0, 0, 0);
  }
}

// ------------------------------------------------------------------ QKV gemm
// z=0: Q (rope+QSCALE) -> (B,H,S,64); z=1: K (rope) -> (B,H,S,64);
// z=2: V -> (B,H,64,S) transposed. RoPE fused via shfl_xor(v,1): the even/odd
// partner of feature d lives in the adjacent lane (col = ...+lr).
template<bool F32>
__global__ __launch_bounds__(256, 2)
void qkv_gemm_kernel(const void* __restrict__ X,
                     const void* __restrict__ Wq, const void* __restrict__ Wk,
                     const void* __restrict__ Wv,
                     const float* __restrict__ cosT, const float* __restrict__ sinT,
                     u16* __restrict__ Qo, u16* __restrict__ Ko, u16* __restrict__ Vto) {
  __shared__ __align__(16) u16 As[128 * 32];
  __shared__ __align__(16) u16 Bs[128 * 32];
  const int z = blockIdx.z;
  const void* W = (z == 0) ? Wq : ((z == 1) ? Wk : Wv);
  const int m0 = blockIdx.x * 128, n0 = blockIdx.y * 128;
  f32x4 acc[4][4] = {};
  gemm128_core<F32, F32>(X, W, As, Bs, m0, n0, acc);
  const int lane = threadIdx.x & 63, wave = threadIdx.x >> 6;
  const int wr = (wave >> 1) * 64, wc = (wave & 1) * 64;
  const int lr = lane & 15, lg = lane >> 4;
  if (z < 2) {
    u16* dst = z ? Ko : Qo;
    const float qs = z ? 1.0f : QSCALE;
    const int parity = lr & 1;
#pragma unroll
    for (int i = 0; i < 4; ++i) {
      const int rb = m0 + wr + i * 16 + lg * 4;  // global row = b*2048+s
#pragma unroll
      for (int n = 0; n < 4; ++n) {
        const int c = n0 + wc + n * 16 + lr;     // feature -> h,d
        const int hh = c >> 6, d = c & 63;
        const int ifr = d >> 1;                  // rope pair index 0..31
#pragma unroll
        for (int j = 0; j < 4; ++j) {
          const int r = rb + j;
          const int s = r & 2047;
          float v = acc[i][n][j];
          float p = __shfl_xor(v, 1);            // partner (other parity)
          float cs = cosT[s * 32 + ifr];
          float sn = sinT[s * 32 + ifr];
          float res = parity ? (p * sn + v * cs) : (v * cs - p * sn);
          dst[(((size_t)(r >> 11) * 16 + hh) * 2048 + s) * 64 + d] =
              f2bf(res * qs);
        }
      }
    }
  } else {  // V transposed: 4 consecutive rows (j) pack into one 8B store
#pragma unroll
    for (int i = 0; i < 4; ++i) {
      const int s0 = m0 + wr + i * 16 + lg * 4;
      const int bb = s0 >> 11, ss = s0 & 2047;
#pragma unroll
      for (int n = 0; n < 4; ++n) {
        const int c = n0 + wc + n * 16 + lr;
        const int hh = c >> 6, d = c & 63;
        u16x4 pk;
#pragma unroll
        for (int j = 0; j < 4; ++j) pk[j] = f2bf(acc[i][n][j]);
        *(u16x4*)(Vto + (((size_t)bb * 16 + hh) * 64 + d) * 2048 + ss) = pk;
      }
    }
  }
}

// ------------------------------------------------------------- flash attention
// Block = 4 waves x 16 q-rows = one 64-row diagonal band; K/V^T tiles
// double-buffered in LDS (global_load_lds, pre-swizzled source). Swapped
// QK^T (S^T in regs, lane owns one q-row); softmax lane-local + 2 shfls;
// defer-max (skip rescale when max doesn't grow by >8 in log2 domain).
template<bool MASKED>
static __device__ __forceinline__ void attn_tile(
    const u16* kb, const u16* vb, int kv0, int qrow,
    const bf16x8 (&qf)[2], u16* Psw,
    f32x4 (&accO)[4], float& m, float& l, int lr, int lg) {
  f32x4 sacc[4] = {};
#pragma unroll
  for (int n = 0; n < 4; ++n)
#pragma unroll
    for (int kk = 0; kk < 2; ++kk) {
      const int gsw = ((((kk << 2) | lg) ^ (lr & 7)) << 3);
      bf16x8 kf = *(const bf16x8*)&kb[(n * 16 + lr) * 64 + gsw];
      sacc[n] = __builtin_amdgcn_mfma_f32_16x16x32_bf16(kf, qf[kk], sacc[n], 0, 0, 0);
    }
  if (MASKED) {
#pragma unroll
    for (int n = 0; n < 4; ++n)
#pragma unroll
      for (int j = 0; j < 4; ++j) {
        const int c = kv0 + n * 16 + lg * 4 + j;
        if (c > qrow) sacc[n][j] = -1e30f;
      }
  }
  // row max via max3 chains (v_max3_f32)
  float t0 = fmaxf(fmaxf(sacc[0][0], sacc[0][1]), sacc[0][2]);
  float t1 = fmaxf(fmaxf(sacc[0][3], sacc[1][0]), sacc[1][1]);
  float t2 = fmaxf(fmaxf(sacc[1][2], sacc[1][3]), sacc[2][0]);
  float t3 = fmaxf(fmaxf(sacc[2][1], sacc[2][2]), sacc[2][3]);
  float t4 = fmaxf(fmaxf(sacc[3][0], sacc[3][1]), sacc[3][2]);
  float tm = fmaxf(fmaxf(t0, t1), fmaxf(fmaxf(t2, t3), fmaxf(t4, sacc[3][3])));
  tm = fmaxf(tm, __shfl_xor(tm, 16));
  tm = fmaxf(tm, __shfl_xor(tm, 32));

  float ssum = 0.f;
  u16x4 pk[4];
  if (__all(tm <= m + 8.0f)) {           // defer: keep old max, no rescale
#pragma unroll
    for (int n = 0; n < 4; ++n)
#pragma unroll
      for (int j = 0; j < 4; ++j) {
        float p = exp2f(sacc[n][j] - m);
        ssum += p;
        pk[n][j] = f2bf(p);
      }
    ssum += __shfl_xor(ssum, 16);
    ssum += __shfl_xor(ssum, 32);
    l += ssum;
  } else {
    const float mn = fmaxf(m, tm);
    const float al = exp2f(m - mn);
    m = mn;
#pragma unroll
    for (int n = 0; n < 4; ++n)
#pragma unroll
      for (int j = 0; j < 4; ++j) {
        float p = exp2f(sacc[n][j] - mn);
        ssum += p;
        pk[n][j] = f2bf(p);
      }
    ssum += __shfl_xor(ssum, 16);
    ssum += __shfl_xor(ssum, 32);
    l = l * al + ssum;
#pragma unroll
    for (int n = 0; n < 4; ++n)
#pragma unroll
      for (int j = 0; j < 4; ++j)
        accO[n][j] *= al;
  }
  // store P row (q = lr): 16B-pair position = pair ^ (lr&7); half = granule&1
#pragma unroll
  for (int n = 0; n < 4; ++n) {
    const int g = n * 4 + lg;
    const int off = ((((g >> 1) ^ (lr & 7)) << 3) | ((g & 1) << 2));
    *(u16x4*)&Psw[lr * 64 + off] = pk[n];
  }
#pragma unroll
  for (int kk = 0; kk < 2; ++kk) {
    const int po = (((kk * 4 + lg) ^ (lr & 7)) << 3);
    bf16x8 pb = *(const bf16x8*)&Psw[lr * 64 + po];  // P[q=lr][kk*32+lg*8..+8]
#pragma unroll
    for (int db = 0; db < 4; ++db) {
      const int gsw = ((((kk << 2) | lg) ^ (lr & 7)) << 3);
      bf16x8 vf = *(const bf16x8*)&vb[(db * 16 + lr) * 64 + gsw];
      accO[db] = __builtin_amdgcn_mfma_f32_16x16x32_bf16(vf, pb, accO[db], 0, 0, 0);
    }
  }
}

// grid (B*16 heads, 32 bands heavy-first), 256 thr = 4 waves x 16 q-rows.
__global__ __launch_bounds__(256, 4)
void flash_attn_kernel(const u16* __restrict__ Q, const u16* __restrict__ K,
                       const u16* __restrict__ Vt, u16* __restrict__ O) {
  __shared__ __align__(16) u16 Klds[2][64 * 64];
  __shared__ __align__(16) u16 Vlds[2][64 * 64];
  __shared__ __align__(16) u16 Ps[4][16 * 64];
  const int bh = blockIdx.x;
  const int qcb = 31 - (int)blockIdx.y;    // heavy-first
  const int b = bh >> 4, h = bh & 15;
  const int tid = threadIdx.x;
  const int wv = tid >> 6, lane = tid & 63;
  const int lr = lane & 15, lg = lane >> 4;
  const int qbase = qcb * 64 + wv * 16;
  const int qrow = qbase + lr;             // this lane's q-row
  const size_t hb = (size_t)bh * (2048 * 64);
  const u16* Qh = Q + hb;
  const u16* Kh = K + hb;
  const u16* Vh = Vt + hb;

  const int sgr = ((lane & 7) ^ (lane >> 3)) << 3;  // pre-swizzled src granule
  const int srw = lane >> 3;                        // 0..7
  auto STAGE = [&](int kv0, int bufi) {
    u16* kbd = Klds[bufi];
    u16* vbd = Vlds[bufi];
#pragma unroll
    for (int i = 0; i < 2; ++i) {
      const int r = wv * 16 + i * 8;
      glds16(Kh + (size_t)(kv0 + r + srw) * 64 + sgr, kbd + r * 64);
      glds16(Vh + (size_t)(r + srw) * 2048 + kv0 + sgr, vbd + r * 64);
    }
  };

  bf16x8 qf[2];
#pragma unroll
  for (int kk = 0; kk < 2; ++kk)
    qf[kk] = *(const bf16x8*)(Qh + (size_t)qrow * 64 + kk * 32 + lg * 8);

  f32x4 accO[4] = {};
  float m = -1e30f, l = 0.f;

  const int nt = qcb + 1;                  // tiles incl. the masked diagonal
  STAGE(0, 0);
  __syncthreads();                         // drain stage-0, all waves ready
  for (int t = 0; t < nt - 1; ++t) {
    STAGE((t + 1) * 64, (t & 1) ^ 1);      // prefetch next into other buffer
    attn_tile<false>(Klds[t & 1], Vlds[t & 1], t * 64, qrow, qf, Ps[wv],
                     accO, m, l, lr, lg);
    __syncthreads();                       // drain prefetch + lds reads
  }
  attn_tile<true>(Klds[(nt - 1) & 1], Vlds[(nt - 1) & 1], (nt - 1) * 64, qrow,
                  qf, Ps[wv], accO, m, l, lr, lg);

  const float inv = 1.0f / l;
#pragma unroll
  for (int db = 0; db < 4; ++db) {
    u16x4 pk;
#pragma unroll
    for (int j = 0; j < 4; ++j) pk[j] = f2bf(accO[db][j] * inv);
    const int d = db * 16 + lg * 4;
    *(u16x4*)&O[((size_t)(b * 2048 + qrow) * 16 + h) * 64 + d] = pk;
  }
}

// ------------------------------------------------------------ output projection
template<bool WF32>
__global__ __launch_bounds__(256, 2)
void out_gemm_kernel(const u16* __restrict__ A, const void* __restrict__ W,
                     float* __restrict__ out) {
  __shared__ __align__(16) u16 As[128 * 32];
  __shared__ __align__(16) u16 Bs[128 * 32];
  const int m0 = blockIdx.x * 128, n0 = blockIdx.y * 128;
  f32x4 acc[4][4] = {};
  gemm128_core<false, WF32>(A, W, As, Bs, m0, n0, acc);
  const int lane = threadIdx.x & 63, wave = threadIdx.x >> 6;
  const int wr = (wave >> 1) * 64, wc = (wave & 1) * 64;
  const int lr = lane & 15, lg = lane >> 4;
#pragma unroll
  for (int i = 0; i < 4; ++i)
#pragma unroll
    for (int n = 0; n < 4; ++n) {
      const int c = n0 + wc + n * 16 + lr;
#pragma unroll
      for (int j = 0; j < 4; ++j) {
        const int r = m0 + wr + i * 16 + lg * 4 + j;
        out[(size_t)r * 1024 + c] = acc[i][n][j];   // f32 store, no rounding
      }
    }
}

// --------------------------------------------------------------------- launch
extern "C" void kernel_launch(void* const* d_in, const int* in_sizes, int n_in,
                              void* d_out, int out_size, void* d_ws, size_t ws_size,
                              hipStream_t stream) {
  const float* x  = (const float*)d_in[0];
  const int*   tp = (const int*)d_in[1];
  const float* Wq = (const float*)d_in[2];
  const float* Wk = (const float*)d_in[3];
  const float* Wv = (const float*)d_in[4];
  const float* Wo = (const float*)d_in[5];
  float* out = (float*)d_out;
  const int B = in_sizes[0] / (2048 * 1024);
  const size_t xel = (size_t)B * 2048 * 1024;        // X elements
  const size_t tsz = xel * sizeof(u16);              // 8MB @ B=2
  const size_t TBL = 2048 * 32 * 2 * sizeof(float);  // cos+sin tables
  // Q,K (bf16) live inside d_out (f32 out = 2*tsz bytes); consumed by flash
  // before out_gemm overwrites. Vt, Ob, tables (+ bf16 copies) in ws.
  u16* Qb = (u16*)d_out;
  u16* Kb = (u16*)((char*)d_out + tsz);
  char* ws = (char*)d_ws;
  u16* Vt = (u16*)(ws);
  u16* Ob = (u16*)(ws + tsz);
  float* cosT = (float*)(ws + 2 * tsz);
  float* sinT = cosT + 2048 * 32;
  u16* Xb  = (u16*)(ws + 2 * tsz + TBL);
  u16* Wb4 = Xb + xel;                               // Wq|Wk|Wv|Wo bf16
  const size_t need = 2 * tsz + TBL + tsz + 4 * (size_t)(1024 * 1024) * sizeof(u16);
  const bool cvt = ws_size >= need;

  rope_tables_kernel<<<dim3(256), dim3(256), 0, stream>>>(tp, cosT, sinT);
  if (cvt) {
    cvt_bf16_kernel<<<dim3((int)(xel / 8 / 256)), dim3(256), 0, stream>>>(x, Xb, (int)(xel / 8));
    cvt_w_kernel<<<dim3(512, 1, 4), dim3(256), 0, stream>>>(Wq, Wk, Wv, Wo, Wb4);
    qkv_gemm_kernel<false><<<dim3(B * 16, 8, 3), dim3(256), 0, stream>>>(
        Xb, Wb4, Wb4 + 1024 * 1024, Wb4 + 2 * 1024 * 1024, cosT, sinT, Qb, Kb, Vt);
  } else {
    qkv_gemm_kernel<true><<<dim3(B * 16, 8, 3), dim3(256), 0, stream>>>(
        x, Wq, Wk, Wv, cosT, sinT, Qb, Kb, Vt);
  }
  flash_attn_kernel<<<dim3(B * 16, 32), dim3(256), 0, stream>>>(Qb, Kb, Vt, Ob);
  if (cvt) {
    out_gemm_kernel<false><<<dim3(B * 16, 8), dim3(256), 0, stream>>>(
        Ob, Wb4 + 3 * 1024 * 1024, out);
  } else {
    out_gemm_kernel<true><<<dim3(B * 16, 8), dim3(256), 0, stream>>>(Ob, Wo, out);
  }
}